// Round 13
// baseline (642.395 us; speedup 1.0000x reference)
//
#include <hip/hip_runtime.h>
#include <math.h>

#define Bb 2
#define Tt 1024
#define Cc 1024
#define Hh 16
#define Dd 64
#define Mm (Bb*Tt)
#define DECAY_SCALE (-0.6065306597126334f)
#define GN_EPS (64e-5f)

typedef __attribute__((ext_vector_type(8))) short short8;   // 8 bf16 (4 VGPRs)
typedef __attribute__((ext_vector_type(4))) float f32x4;    // MFMA acc

struct GemmDesc {
  const float* A;      // used when mixrow < 0 (row stride = K)
  const float* W;      // (N, K) row-major
  float* out;          // (M, N) row-major
  const float* bias;   // per-n bias or nullptr
  int N, K;
  int mixrow;          // >=0: A = token-shift mix of hidden_states with x_mix[mixrow]
  int ep;              // 0 none, 1 tanh, 2 sigmoid(x+bias?), 3 DECAY*sigmoid(x+bias)
};

__device__ __forceinline__ float4 ld4(const float* p){ return *reinterpret_cast<const float4*>(p); }
__device__ __forceinline__ float sigmf(float x){ return 1.f/(1.f+expf(-x)); }

__device__ __forceinline__ float wredsum(float x){
  #pragma unroll
  for (int off=32; off>0; off>>=1) x += __shfl_xor(x, off);
  return x;
}

template<int CTRL>
__device__ __forceinline__ float dppadd(float x){
  return x + __int_as_float(__builtin_amdgcn_update_dpp(0, __float_as_int(x), CTRL, 0xF, 0xF, true));
}

// 16-lane sum (lanes 16k..16k+15), pure DPP (VALU speed, no LDS pipe).
__device__ __forceinline__ float dsum16(float x){
  x = dppadd<0xB1>(x);
  x = dppadd<0x4E>(x);
  x = dppadd<0x141>(x);
  x = dppadd<0x140>(x);
  return x;
}

// two independent 16-lane sums, explicitly interleaved so the second chain's
// DPP latency hides under the first chain's stalls (single-wave in-order issue).
__device__ __forceinline__ void dsum16x2(float& x, float& y){
  x = dppadd<0xB1>(x);  y = dppadd<0xB1>(y);
  x = dppadd<0x4E>(x);  y = dppadd<0x4E>(y);
  x = dppadd<0x141>(x); y = dppadd<0x141>(y);
  x = dppadd<0x140>(x); y = dppadd<0x140>(y);
}

// async global -> LDS DMA (16 B / 4 B per lane); dest = wave-uniform base + lane*size
__device__ __forceinline__ void gl2lds16(const float* g, float* l){
  __builtin_amdgcn_global_load_lds(
      (const __attribute__((address_space(1))) unsigned int*)g,
      (__attribute__((address_space(3))) unsigned int*)l, 16, 0, 0);
}
__device__ __forceinline__ void gl2lds4(const float* g, float* l){
  __builtin_amdgcn_global_load_lds(
      (const __attribute__((address_space(1))) unsigned int*)g,
      (__attribute__((address_space(3))) unsigned int*)l, 4, 0, 0);
}

// split one fp32 value pair into packed bf16 hi/lo words
__device__ __forceinline__ void split2(const float a, const float b,
                                       unsigned& hw, unsigned& lw){
  unsigned u0 = __float_as_uint(a);
  unsigned u1 = __float_as_uint(b);
  float l0 = a - __uint_as_float(u0 & 0xFFFF0000u);
  float l1 = b - __uint_as_float(u1 & 0xFFFF0000u);
  hw = (u0>>16) | (u1 & 0xFFFF0000u);
  lw = (__float_as_uint(l0)>>16) | (__float_as_uint(l1) & 0xFFFF0000u);
}

#define BM 64
#define BN 128
#define BK 32
#define TM 128
#define TN 128
#define LDBS 40   // bf16 row stride in LDS

// ---------------- vector-ALU GEMM (LoRA stage-2 standalone launch) ----------------
__global__ __launch_bounds__(256) void gemm_kernel(
    GemmDesc d0, GemmDesc d1, GemmDesc d2, GemmDesc d3,
    const float* __restrict__ xmix, const float* __restrict__ hs)
{
  GemmDesc d = (blockIdx.z==0)?d0:(blockIdx.z==1)?d1:(blockIdx.z==2)?d2:d3;
  const int n0 = blockIdx.x * BN;
  if (n0 >= d.N) return;            // block-uniform
  const int m0 = blockIdx.y * BM;
  const int tid = threadIdx.x;
  __shared__ float As[BK][BM+4];
  __shared__ float Bs[BK][BN+4];
  const int ty = tid >> 4, tx = tid & 15;

  float acc[4][8];
  #pragma unroll
  for (int i=0;i<4;++i)
    #pragma unroll
    for (int j=0;j<8;++j) acc[i][j]=0.f;

  const int K = d.K;
  const int nt = K / BK;
  const float* mrow = (d.mixrow >= 0) ? (xmix + (size_t)d.mixrow * Cc) : nullptr;
  float4 pa[2], pb[4];

  auto load_tile = [&](int kt){
    const int kbase = kt * BK;
    #pragma unroll
    for (int u=0;u<2;++u){
      const int li = tid + u*256;
      const int ar = li >> 3;
      const int kk = ((li & 7) << 2) + kbase;
      const int gm = m0 + ar;
      if (mrow){
        float4 h0 = ld4(hs + (size_t)gm*Cc + kk);
        float4 mx = ld4(mrow + kk);
        float4 hp = make_float4(0.f,0.f,0.f,0.f);
        if ((gm & (Tt-1)) != 0) hp = ld4(hs + (size_t)(gm-1)*Cc + kk);
        pa[u].x = h0.x + (hp.x - h0.x)*mx.x;
        pa[u].y = h0.y + (hp.y - h0.y)*mx.y;
        pa[u].z = h0.z + (hp.z - h0.z)*mx.z;
        pa[u].w = h0.w + (hp.w - h0.w)*mx.w;
      } else {
        pa[u] = ld4(d.A + (size_t)gm*K + kk);
      }
    }
    #pragma unroll
    for (int u=0;u<4;++u){
      const int li = tid + u*256;
      const int br = li >> 3;
      const int kk = ((li & 7) << 2) + kbase;
      const int gn = n0 + br;
      pb[u] = (gn < d.N) ? ld4(d.W + (size_t)gn*K + kk) : make_float4(0.f,0.f,0.f,0.f);
    }
  };

  load_tile(0);
  for (int kt=0; kt<nt; ++kt){
    __syncthreads();
    #pragma unroll
    for (int u=0;u<2;++u){
      const int li = tid + u*256;
      const int ar = li >> 3;
      const int kc = (li & 7) << 2;
      As[kc+0][ar] = pa[u].x; As[kc+1][ar] = pa[u].y;
      As[kc+2][ar] = pa[u].z; As[kc+3][ar] = pa[u].w;
    }
    #pragma unroll
    for (int u=0;u<4;++u){
      const int li = tid + u*256;
      const int br = li >> 3;
      const int kc = (li & 7) << 2;
      Bs[kc+0][br] = pb[u].x; Bs[kc+1][br] = pb[u].y;
      Bs[kc+2][br] = pb[u].z; Bs[kc+3][br] = pb[u].w;
    }
    __syncthreads();
    if (kt+1 < nt) load_tile(kt+1);
    #pragma unroll
    for (int kk=0;kk<BK;++kk){
      const float4 a0 = *(const float4*)&As[kk][ty<<2];
      const float4 b0 = *(const float4*)&Bs[kk][tx<<3];
      const float4 b1 = *(const float4*)&Bs[kk][(tx<<3)+4];
      const float av[4] = {a0.x,a0.y,a0.z,a0.w};
      const float bv[8] = {b0.x,b0.y,b0.z,b0.w,b1.x,b1.y,b1.z,b1.w};
      #pragma unroll
      for (int i=0;i<4;++i)
        #pragma unroll
        for (int j=0;j<8;++j)
          acc[i][j] = fmaf(av[i], bv[j], acc[i][j]);
    }
  }

  const int ep = d.ep;
  #pragma unroll
  for (int i=0;i<4;++i){
    const int gm = m0 + (ty<<2) + i;
    float* orow = d.out + (size_t)gm * d.N;
    #pragma unroll
    for (int j=0;j<8;++j){
      const int gn = n0 + (tx<<3) + j;
      if (gn < d.N){
        float x = acc[i][j];
        if (ep==1) x = tanhf(x);
        else if (ep==2){ if (d.bias) x += d.bias[gn]; x = sigmf(x); }
        else if (ep==3){ x += d.bias[gn]; x = DECAY_SCALE * sigmf(x); }
        orow[gn] = x;
      }
    }
  }
}

// ---------------- weight split pre-pass (fp32 -> bf16 hi/lo planes) ----------------
#define NPL (Cc*Cc)
__global__ __launch_bounds__(256) void wsplit_kernel(
    const float* __restrict__ s0, const float* __restrict__ s1,
    const float* __restrict__ s2, const float* __restrict__ s3,
    unsigned short* __restrict__ planes)
{
  const int z = blockIdx.z;
  const float* src = z==0?s0:z==1?s1:z==2?s2:s3;
  unsigned short* dh = planes + (size_t)z*2*NPL;
  unsigned short* dl = dh + NPL;
  const size_t i = ((size_t)blockIdx.x*256 + threadIdx.x)*4;
  float4 v = ld4(src + i);
  unsigned hw0, lw0, hw1, lw1;
  split2(v.x, v.y, hw0, lw0);
  split2(v.z, v.w, hw1, lw1);
  uint2 hv; hv.x = hw0; hv.y = hw1;
  uint2 lv; lv.x = lw0; lv.y = lw1;
  *(uint2*)(dh + i) = hv;
  *(uint2*)(dl + i) = lv;
}

// ---------------- fp32 premix pre-pass (token-shift mix only, NO split) -----------
__global__ __launch_bounds__(256) void premix_kernel(
    const float* __restrict__ hs, const float* __restrict__ xmix,
    float* __restrict__ p0, float* __restrict__ p1, float* __restrict__ p2)
{
  const int z = blockIdx.z;
  float* ph = z==0?p0:(z==1?p1:p2);
  const int mr = z==0?0:(z==1?2:3);
  const size_t o = ((size_t)blockIdx.x*256 + threadIdx.x)*4;
  const int gm = (int)(o >> 10);          // Cc = 1024
  const int kk = (int)(o & 1023);
  float4 h0 = ld4(hs + o);
  float4 mx = ld4(xmix + (size_t)mr*Cc + kk);
  float4 hp = make_float4(0.f,0.f,0.f,0.f);
  if ((gm & (Tt-1)) != 0) hp = ld4(hs + o - Cc);
  float4 r;
  r.x = h0.x + (hp.x - h0.x)*mx.x;
  r.y = h0.y + (hp.y - h0.y)*mx.y;
  r.z = h0.z + (hp.z - h0.z)*mx.z;
  r.w = h0.w + (hp.w - h0.w)*mx.w;
  *(float4*)(ph + o) = r;
}

// ---------------- fused L1+L2: MFMA projections || vector-ALU LoRA stage-1 --------
// blocks 0..383: split-bf16 MFMA projections r/k0/v0 (TM=128, bit-identical body).
// blocks 384..639: LoRA stage-1 GEMMs on the VECTOR pipe (bit-identical body).
// The two groups are data-independent and use different execution pipes; fusing
// them into one launch lets the CU scheduler overlap LoRA VALU work with the
// MFMA blocks' barrier/LDS slack (m114: MFMA+VALU co-schedule ~ max, not sum).
__global__ __launch_bounds__(256) void proj_lora_kernel(
    GemmDesc d0, GemmDesc d1, GemmDesc d2,
    const unsigned short* __restrict__ WH0, const unsigned short* __restrict__ WL0,
    const unsigned short* __restrict__ WH1, const unsigned short* __restrict__ WL1,
    const unsigned short* __restrict__ WH2, const unsigned short* __restrict__ WL2,
    GemmDesc e0, GemmDesc e1, GemmDesc e2, GemmDesc e3,
    const float* __restrict__ xmix, const float* __restrict__ hs)
{
  __shared__ __align__(16) unsigned char SMEM[40960];
  const int bid = blockIdx.x;
  const int tid = threadIdx.x;

  if (bid < 384){
    // ================= MFMA projection path =================
    const int z = bid >> 7;           // slice 0..2 (128 blocks each: 8 x 16)
    const int rem = bid & 127;
    const int m0 = (rem >> 3) * TM;
    const int n0 = (rem & 7) * TN;
    GemmDesc d = z==0?d0:(z==1?d1:d2);
    const unsigned short* WH = z==0?WH0:(z==1?WH1:WH2);
    const unsigned short* WL = z==0?WL0:(z==1?WL1:WL2);
    const int K = d.K;

    unsigned short* Ah = (unsigned short*)SMEM;
    unsigned short* Al = Ah + TM*LDBS;
    unsigned short* Bh = Al + TM*LDBS;
    unsigned short* Bl = Bh + TM*LDBS;

    const int sr = tid >> 1;
    const int sk = (tid & 1) << 4;
    const int gmA = m0 + sr;
    const int gnB = n0 + sr;

    float4 pa[4];
    uint4 pwh[2], pwl[2];
    auto load_slab = [&](int kt){
      const int kb = kt*32 + sk;
      #pragma unroll
      for (int u=0;u<4;++u)
        pa[u] = ld4(d.A + (size_t)gmA*K + kb + 4*u);
      pwh[0] = *(const uint4*)(WH + (size_t)gnB*K + kb);
      pwh[1] = *(const uint4*)(WH + (size_t)gnB*K + kb + 8);
      pwl[0] = *(const uint4*)(WL + (size_t)gnB*K + kb);
      pwl[1] = *(const uint4*)(WL + (size_t)gnB*K + kb + 8);
    };

    const int wv = tid >> 6, lane = tid & 63;
    const int wm = (wv >> 1) << 6, wn = (wv & 1) << 6;
    const int fr = lane & 15;
    const int fk = (lane >> 4) << 3;

    f32x4 acc[4][4];
    const f32x4 z4 = {0.f,0.f,0.f,0.f};
    #pragma unroll
    for (int i=0;i<4;++i)
      #pragma unroll
      for (int j=0;j<4;++j) acc[i][j]=z4;

    const int nslab = K >> 5;
    load_slab(0);
    for (int kt=0; kt<nslab; ++kt){
      __syncthreads();
      {
        unsigned hw[8], lw[8];
        #pragma unroll
        for (int u=0;u<4;++u){
          const float xs[4] = {pa[u].x, pa[u].y, pa[u].z, pa[u].w};
          split2(xs[0], xs[1], hw[u*2+0], lw[u*2+0]);
          split2(xs[2], xs[3], hw[u*2+1], lw[u*2+1]);
        }
        uint4 t;
        t.x=hw[0];t.y=hw[1];t.z=hw[2];t.w=hw[3]; *(uint4*)&Ah[sr*LDBS+sk]   = t;
        t.x=hw[4];t.y=hw[5];t.z=hw[6];t.w=hw[7]; *(uint4*)&Ah[sr*LDBS+sk+8] = t;
        t.x=lw[0];t.y=lw[1];t.z=lw[2];t.w=lw[3]; *(uint4*)&Al[sr*LDBS+sk]   = t;
        t.x=lw[4];t.y=lw[5];t.z=lw[6];t.w=lw[7]; *(uint4*)&Al[sr*LDBS+sk+8] = t;
        *(uint4*)&Bh[sr*LDBS+sk]   = pwh[0];
        *(uint4*)&Bh[sr*LDBS+sk+8] = pwh[1];
        *(uint4*)&Bl[sr*LDBS+sk]   = pwl[0];
        *(uint4*)&Bl[sr*LDBS+sk+8] = pwl[1];
      }
      __syncthreads();
      if (kt+1 < nslab) load_slab(kt+1);

      short8 bh4[4], bl4[4];
      #pragma unroll
      for (int nt=0;nt<4;++nt){
        bh4[nt] = *(const short8*)&Bh[(wn + nt*16 + fr)*LDBS + fk];
        bl4[nt] = *(const short8*)&Bl[(wn + nt*16 + fr)*LDBS + fk];
      }
      #pragma unroll
      for (int mt=0;mt<4;++mt){
        const short8 ah = *(const short8*)&Ah[(wm + mt*16 + fr)*LDBS + fk];
        const short8 al = *(const short8*)&Al[(wm + mt*16 + fr)*LDBS + fk];
        #pragma unroll
        for (int nt=0;nt<4;++nt)
          acc[mt][nt] = __builtin_amdgcn_mfma_f32_16x16x32_bf16(ah, bh4[nt], acc[mt][nt], 0,0,0);
        #pragma unroll
        for (int nt=0;nt<4;++nt)
          acc[mt][nt] = __builtin_amdgcn_mfma_f32_16x16x32_bf16(ah, bl4[nt], acc[mt][nt], 0,0,0);
        #pragma unroll
        for (int nt=0;nt<4;++nt)
          acc[mt][nt] = __builtin_amdgcn_mfma_f32_16x16x32_bf16(al, bh4[nt], acc[mt][nt], 0,0,0);
      }
    }

    #pragma unroll
    for (int mt=0;mt<4;++mt){
      #pragma unroll
      for (int nt=0;nt<4;++nt){
        #pragma unroll
        for (int r=0;r<4;++r){
          const int row = wm + mt*16 + ((lane>>4)<<2) + r;
          const int col = wn + nt*16 + fr;
          d.out[(size_t)(m0+row)*d.N + n0 + col] = acc[mt][nt][r];
        }
      }
    }
  } else {
    // ================= vector-ALU LoRA stage-1 path =================
    const int inner = bid - 384;
    const int z = inner >> 6;
    const int rem = inner & 63;
    GemmDesc d = (z==0)?e0:(z==1)?e1:(z==2)?e2:e3;
    const int n0 = (rem & 1) * BN;
    if (n0 >= d.N) return;
    const int m0 = (rem >> 1) * BM;

    float (*As)[BM+4] = reinterpret_cast<float(*)[BM+4]>(SMEM);
    float (*Bs)[BN+4] = reinterpret_cast<float(*)[BN+4]>(SMEM + sizeof(float)*BK*(BM+4));
    const int ty = tid >> 4, tx = tid & 15;

    float acc[4][8];
    #pragma unroll
    for (int i=0;i<4;++i)
      #pragma unroll
      for (int j=0;j<8;++j) acc[i][j]=0.f;

    const int K = d.K;
    const int nt = K / BK;
    const float* mrow = (d.mixrow >= 0) ? (xmix + (size_t)d.mixrow * Cc) : nullptr;
    float4 pa[2], pb[4];

    auto load_tile = [&](int kt){
      const int kbase = kt * BK;
      #pragma unroll
      for (int u=0;u<2;++u){
        const int li = tid + u*256;
        const int ar = li >> 3;
        const int kk = ((li & 7) << 2) + kbase;
        const int gm = m0 + ar;
        if (mrow){
          float4 h0 = ld4(hs + (size_t)gm*Cc + kk);
          float4 mx = ld4(mrow + kk);
          float4 hp = make_float4(0.f,0.f,0.f,0.f);
          if ((gm & (Tt-1)) != 0) hp = ld4(hs + (size_t)(gm-1)*Cc + kk);
          pa[u].x = h0.x + (hp.x - h0.x)*mx.x;
          pa[u].y = h0.y + (hp.y - h0.y)*mx.y;
          pa[u].z = h0.z + (hp.z - h0.z)*mx.z;
          pa[u].w = h0.w + (hp.w - h0.w)*mx.w;
        } else {
          pa[u] = ld4(d.A + (size_t)gm*K + kk);
        }
      }
      #pragma unroll
      for (int u=0;u<4;++u){
        const int li = tid + u*256;
        const int br = li >> 3;
        const int kk = ((li & 7) << 2) + kbase;
        const int gn = n0 + br;
        pb[u] = (gn < d.N) ? ld4(d.W + (size_t)gn*K + kk) : make_float4(0.f,0.f,0.f,0.f);
      }
    };

    load_tile(0);
    for (int kt=0; kt<nt; ++kt){
      __syncthreads();
      #pragma unroll
      for (int u=0;u<2;++u){
        const int li = tid + u*256;
        const int ar = li >> 3;
        const int kc = (li & 7) << 2;
        As[kc+0][ar] = pa[u].x; As[kc+1][ar] = pa[u].y;
        As[kc+2][ar] = pa[u].z; As[kc+3][ar] = pa[u].w;
      }
      #pragma unroll
      for (int u=0;u<4;++u){
        const int li = tid + u*256;
        const int br = li >> 3;
        const int kc = (li & 7) << 2;
        Bs[kc+0][br] = pb[u].x; Bs[kc+1][br] = pb[u].y;
        Bs[kc+2][br] = pb[u].z; Bs[kc+3][br] = pb[u].w;
      }
      __syncthreads();
      if (kt+1 < nt) load_tile(kt+1);
      #pragma unroll
      for (int kk=0;kk<BK;++kk){
        const float4 a0 = *(const float4*)&As[kk][ty<<2];
        const float4 b0 = *(const float4*)&Bs[kk][tx<<3];
        const float4 b1 = *(const float4*)&Bs[kk][(tx<<3)+4];
        const float av[4] = {a0.x,a0.y,a0.z,a0.w};
        const float bv[8] = {b0.x,b0.y,b0.z,b0.w,b1.x,b1.y,b1.z,b1.w};
        #pragma unroll
        for (int i=0;i<4;++i)
          #pragma unroll
          for (int j=0;j<8;++j)
            acc[i][j] = fmaf(av[i], bv[j], acc[i][j]);
      }
    }

    const int ep = d.ep;
    #pragma unroll
    for (int i=0;i<4;++i){
      const int gm = m0 + (ty<<2) + i;
      float* orow = d.out + (size_t)gm * d.N;
      #pragma unroll
      for (int j=0;j<8;++j){
        const int gn = n0 + (tx<<3) + j;
        if (gn < d.N){
          float x = acc[i][j];
          if (ep==1) x = tanhf(x);
          else if (ep==2){ if (d.bias) x += d.bias[gn]; x = sigmf(x); }
          else if (ep==3){ x += d.bias[gn]; x = DECAY_SCALE * sigmf(x); }
          orow[gn] = x;
        }
      }
    }
  }
}

// ---------------- split-bf16 MFMA GEMM (standalone, for L7) ----------------
__global__ __launch_bounds__(256) void gemm_mfma(
    GemmDesc d0, GemmDesc d1, GemmDesc d2,
    const unsigned short* __restrict__ WH0, const unsigned short* __restrict__ WL0,
    const unsigned short* __restrict__ WH1, const unsigned short* __restrict__ WL1,
    const unsigned short* __restrict__ WH2, const unsigned short* __restrict__ WL2)
{
  const int z = blockIdx.z;
  GemmDesc d = z==0?d0:(z==1?d1:d2);
  const unsigned short* WH = z==0?WH0:(z==1?WH1:WH2);
  const unsigned short* WL = z==0?WL0:(z==1?WL1:WL2);
  const int m0 = blockIdx.y * TM;
  const int n0 = blockIdx.x * TN;
  const int K  = d.K;
  const int tid = threadIdx.x;

  __shared__ __align__(16) unsigned short Ah[TM*LDBS], Al[TM*LDBS];
  __shared__ __align__(16) unsigned short Bh[TN*LDBS], Bl[TN*LDBS];

  const int sr = tid >> 1;
  const int sk = (tid & 1) << 4;
  const int gmA = m0 + sr;
  const int gnB = n0 + sr;

  float4 pa[4];
  uint4 pwh[2], pwl[2];
  auto load_slab = [&](int kt){
    const int kb = kt*32 + sk;
    #pragma unroll
    for (int u=0;u<4;++u)
      pa[u] = ld4(d.A + (size_t)gmA*K + kb + 4*u);
    pwh[0] = *(const uint4*)(WH + (size_t)gnB*K + kb);
    pwh[1] = *(const uint4*)(WH + (size_t)gnB*K + kb + 8);
    pwl[0] = *(const uint4*)(WL + (size_t)gnB*K + kb);
    pwl[1] = *(const uint4*)(WL + (size_t)gnB*K + kb + 8);
  };

  const int wv = tid >> 6, lane = tid & 63;
  const int wm = (wv >> 1) << 6, wn = (wv & 1) << 6;
  const int fr = lane & 15;
  const int fk = (lane >> 4) << 3;

  f32x4 acc[4][4];
  const f32x4 z4 = {0.f,0.f,0.f,0.f};
  #pragma unroll
  for (int i=0;i<4;++i)
    #pragma unroll
    for (int j=0;j<4;++j) acc[i][j]=z4;

  const int nslab = K >> 5;
  load_slab(0);
  for (int kt=0; kt<nslab; ++kt){
    __syncthreads();
    {
      unsigned hw[8], lw[8];
      #pragma unroll
      for (int u=0;u<4;++u){
        const float xs[4] = {pa[u].x, pa[u].y, pa[u].z, pa[u].w};
        split2(xs[0], xs[1], hw[u*2+0], lw[u*2+0]);
        split2(xs[2], xs[3], hw[u*2+1], lw[u*2+1]);
      }
      uint4 t;
      t.x=hw[0];t.y=hw[1];t.z=hw[2];t.w=hw[3]; *(uint4*)&Ah[sr*LDBS+sk]   = t;
      t.x=hw[4];t.y=hw[5];t.z=hw[6];t.w=hw[7]; *(uint4*)&Ah[sr*LDBS+sk+8] = t;
      t.x=lw[0];t.y=lw[1];t.z=lw[2];t.w=lw[3]; *(uint4*)&Al[sr*LDBS+sk]   = t;
      t.x=lw[4];t.y=lw[5];t.z=lw[6];t.w=lw[7]; *(uint4*)&Al[sr*LDBS+sk+8] = t;
      *(uint4*)&Bh[sr*LDBS+sk]   = pwh[0];
      *(uint4*)&Bh[sr*LDBS+sk+8] = pwh[1];
      *(uint4*)&Bl[sr*LDBS+sk]   = pwl[0];
      *(uint4*)&Bl[sr*LDBS+sk+8] = pwl[1];
    }
    __syncthreads();
    if (kt+1 < nslab) load_slab(kt+1);

    short8 bh4[4], bl4[4];
    #pragma unroll
    for (int nt=0;nt<4;++nt){
      bh4[nt] = *(const short8*)&Bh[(wn + nt*16 + fr)*LDBS + fk];
      bl4[nt] = *(const short8*)&Bl[(wn + nt*16 + fr)*LDBS + fk];
    }
    #pragma unroll
    for (int mt=0;mt<4;++mt){
      const short8 ah = *(const short8*)&Ah[(wm + mt*16 + fr)*LDBS + fk];
      const short8 al = *(const short8*)&Al[(wm + mt*16 + fr)*LDBS + fk];
      #pragma unroll
      for (int nt=0;nt<4;++nt)
        acc[mt][nt] = __builtin_amdgcn_mfma_f32_16x16x32_bf16(ah, bh4[nt], acc[mt][nt], 0,0,0);
      #pragma unroll
      for (int nt=0;nt<4;++nt)
        acc[mt][nt] = __builtin_amdgcn_mfma_f32_16x16x32_bf16(ah, bl4[nt], acc[mt][nt], 0,0,0);
      #pragma unroll
      for (int nt=0;nt<4;++nt)
        acc[mt][nt] = __builtin_amdgcn_mfma_f32_16x16x32_bf16(al, bh4[nt], acc[mt][nt], 0,0,0);
    }
  }

  #pragma unroll
  for (int mt=0;mt<4;++mt){
    #pragma unroll
    for (int nt=0;nt<4;++nt){
      #pragma unroll
      for (int r=0;r<4;++r){
        const int row = wm + mt*16 + ((lane>>4)<<2) + r;
        const int col = wn + nt*16 + fr;
        d.out[(size_t)(m0+row)*d.N + n0 + col] = acc[mt][nt][r];
      }
    }
  }
}

// ---------------- per-head prep (in-place coefficient precompute) ----------------
__global__ __launch_bounds__(256) void head_prep(
    float* kbuf, float* awbuf, float* svwbuf, float* wbbuf, float* vbuf,
    const float* __restrict__ vfirst,
    const float* __restrict__ k_k, const float* __restrict__ k_a)
{
  const int gid = blockIdx.x*4 + (threadIdx.x>>6);
  const int e = threadIdx.x & 63;
  const int m = gid >> 4;
  const int h = gid & 15;
  const int c = h*Dd + e;
  const size_t idx = (size_t)m*Cc + c;
  const float kv0 = kbuf[idx];
  const float av  = awbuf[idx];
  const float sv  = svwbuf[idx];
  const float wv  = wbbuf[idx];
  const float v0  = vbuf[idx];
  const float vf  = vfirst[idx];
  const float kku = kv0 * k_k[c];
  const float ss  = wredsum(kku*kku);
  const float kkn = kku / fmaxf(sqrtf(ss), 1e-12f);
  const float ew  = expf(wv);
  kbuf[idx]  = kv0 * (1.f + (av - 1.f)*k_a[c]);
  awbuf[idx] = ew;
  svwbuf[idx]= -kkn * ew;
  wbbuf[idx] = kkn * av;
  vbuf[idx]  = v0 + sv*(vf - v0);
}

// ---------------- sequential scan v13: 4-deep register pipeline + counted vmcnt ----
#define NB (Tt/16)
struct Coef { float4 Lw, Ew, Bq, Kq, Rq; float Vv; };
__global__ __launch_bounds__(64) void scan_kernel(
    const float* __restrict__ lawb, const float* __restrict__ ewb,
    const float* __restrict__ bbb,  const float* __restrict__ kb,
    const float* __restrict__ rb,   const float* __restrict__ vb,
    float* __restrict__ outp)
{
  const int blk  = blockIdx.x;
  const int bh   = blk & 31;        // chain id; 16 blocks %32-congruent -> same XCD
  const int blkc = blk >> 5;        // 0..15: column quad
  const int b = bh >> 4, h = bh & 15;
  const int lane = threadIdx.x;
  const int es = lane >> 4;         // column slot 0..3
  const int rd = lane & 15;         // row quad (rows 4rd..4rd+3)
  const int colb = blkc * 4;
  const int hb = h * Dd;
  const int la = 4*rd;              // dword offset of this lane's row quad

  // per buffer: law[1024] ew[1024] bb[1024] k[1024] r[1024] v[64]
  __shared__ __align__(16) float LB[2][5*1024 + 64];

  float S0=0.f, S1=0.f, S2=0.f, S3=0.f;
  float4 Rp = make_float4(0.f,0.f,0.f,0.f);   // r of previous step (r_{g-1})
  const size_t mbase = (size_t)b*Tt;
  float* ocol = outp + mbase*Cc + hb + colb + es;   // column base for rd==0 stores

  const int qrow = lane >> 4;           // staging: row within 4-row slab
  const int qcol = (lane & 15) * 4;     // staging: dword col

  auto stage = [&](int bt){
    const size_t g0 = (mbase + (size_t)bt*16)*Cc + hb;
    float* dst = &LB[bt&1][0];
    const float* srcs[5] = {lawb, ewb, bbb, kb, rb};
    #pragma unroll
    for (int a=0;a<5;++a){
      const float* s = srcs[a] + g0 + (size_t)qrow*Cc + qcol;
      #pragma unroll
      for (int i=0;i<4;++i)
        gl2lds16(s + (size_t)(4*i)*Cc, dst + a*1024 + i*256);
    }
    gl2lds4(vb + g0 + (size_t)(lane>>2)*Cc + colb + (lane&3), dst + 5120);
  };

  stage(0);
  __builtin_amdgcn_s_waitcnt(0x0F70);   // vmcnt(0): batch 0's DMA complete

  for (int bt = 0; bt < NB; ++bt){
    if (bt+1 < NB) stage(bt+1);           // in flight under this batch's compute
    const float* cb2 = &LB[bt&1][0];

    auto ldq = [&](int t, Coef& c){
      c.Lw = *(const float4*)&cb2[         t*64 + la];
      c.Ew = *(const float4*)&cb2[1024 + t*64 + la];
      c.Bq = *(const float4*)&cb2[2048 + t*64 + la];
      c.Kq = *(const float4*)&cb2[3072 + t*64 + la];
      c.Rq = *(const float4*)&cb2[4096 + t*64 + la];
      c.Vv = cb2[5120 + t*4 + es];
    };

    Coef cA, cB, cC, cD;
    ldq(0, cA); ldq(1, cB); ldq(2, cC); ldq(3, cD);

    auto stepf = [&](int t, Coef& c){
      const float4 Lw = c.Lw, Ew = c.Ew, Bq = c.Bq, Kq = c.Kq, rr = c.Rq;
      const float vv = c.Vv;
      // both dots read S_old: ta for THIS step's update, op for PREVIOUS step's output
      float tp = fmaf(Lw.y, S1, Lw.x*S0);
      float tb = fmaf(Lw.w, S3, Lw.z*S2);
      tp += tb;
      float op = fmaf(Rp.y, S1, Rp.x*S0);
      float ob = fmaf(Rp.w, S3, Rp.z*S2);
      op += ob;
      dsum16x2(tp, op);                       // interleaved: op hides under tp's chain
      // store out(g-1); only batch 0 / t==0 has no predecessor
      const bool gv = (bt > 0) | (t > 0);
      if (gv && rd == 0)
        ocol[(size_t)(bt*16 + t - 1)*Cc] = op;
      S0 = fmaf(Ew.x, S0, fmaf(Bq.x, tp, Kq.x*vv));
      S1 = fmaf(Ew.y, S1, fmaf(Bq.y, tp, Kq.y*vv));
      S2 = fmaf(Ew.z, S2, fmaf(Bq.z, tp, Kq.z*vv));
      S3 = fmaf(Ew.w, S3, fmaf(Bq.w, tp, Kq.w*vv));
      Rp = rr;                                // r_g becomes r_{g-1} for next step
      if (t+4 < 16) ldq(t+4, c);              // refill same buffer, 4 steps ahead
    };

    #pragma unroll
    for (int t = 0; t < 16; ++t){
      const int s = t & 3;
      if      (s == 0) stepf(t, cA);
      else if (s == 1) stepf(t, cB);
      else if (s == 2) stepf(t, cC);
      else             stepf(t, cD);
    }

    // counted wait: stage(bt+1)'s 22 DMA ops are the OLDEST outstanding vm ops;
    // <=16 output stores were issued after them. vmcnt(16) => all DMA landed.
    if (bt+1 < NB) __builtin_amdgcn_s_waitcnt(0x4F70);   // vmcnt(16)
  }

  // flush: out(T-1) = r_{T-1} . S(T-1)
  {
    float op = fmaf(Rp.y, S1, Rp.x*S0);
    float ob = fmaf(Rp.w, S3, Rp.z*S2);
    op = dsum16(op + ob);
    if (rd == 0)
      ocol[(size_t)(Tt - 1)*Cc] = op;
  }
}

// ---------------- GroupNorm + correction + g gating ----------------
__global__ __launch_bounds__(256) void epilogue_kernel(
    const float* __restrict__ att, const float* __restrict__ rbuf,
    const float* __restrict__ kbuf, const float* __restrict__ vbuf,
    const float* __restrict__ gbuf,
    const float* __restrict__ r_k, const float* __restrict__ gn_w,
    const float* __restrict__ gn_b, float* __restrict__ opre)
{
  const int gid = blockIdx.x*4 + (threadIdx.x>>6);
  const int e = threadIdx.x & 63;
  const int m = gid >> 4;
  const int h = gid & 15;
  const int c = h*Dd + e;
  const size_t idx = (size_t)m*Cc + c;
  const float x  = att[idx];
  const float mu = wredsum(x) * (1.f/Dd);
  const float xd = x - mu;
  const float var = wredsum(xd*xd) * (1.f/Dd);
  const float og = xd * (1.f/sqrtf(var + GN_EPS)) * gn_w[c] + gn_b[c];
  const float rv = rbuf[idx], kv = kbuf[idx], vv = vbuf[idx];
  const float cd = wredsum(rv*kv*r_k[c]);
  opre[idx] = (og + cd*vv) * gbuf[idx];
}

extern "C" void kernel_launch(void* const* d_in, const int* in_sizes, int n_in,
                              void* d_out, int out_size, void* d_ws, size_t ws_size,
                              hipStream_t stream)
{
  (void)in_sizes; (void)n_in; (void)out_size; (void)ws_size;
  const float* hs     = (const float*)d_in[0];
  const float* vfirst = (const float*)d_in[1];
  const float* xmix   = (const float*)d_in[2];
  const float* k_k    = (const float*)d_in[3];
  const float* k_a    = (const float*)d_in[4];
  const float* r_k    = (const float*)d_in[5];
  const float* W_r    = (const float*)d_in[6];
  const float* W_k    = (const float*)d_in[7];
  const float* W_v    = (const float*)d_in[8];
  const float* W_o    = (const float*)d_in[9];
  const float* w_A    = (const float*)d_in[10];
  const float* w_B    = (const float*)d_in[11];
  const float* w_b    = (const float*)d_in[12];
  const float* a_A    = (const float*)d_in[13];
  const float* a_B    = (const float*)d_in[14];
  const float* a_b    = (const float*)d_in[15];
  const float* v_A    = (const float*)d_in[16];
  const float* v_B    = (const float*)d_in[17];
  const float* v_b    = (const float*)d_in[18];
  const float* g_A    = (const float*)d_in[19];
  const float* g_B    = (const float*)d_in[20];
  const float* gn_w   = (const float*)d_in[21];
  const float* gn_b   = (const float*)d_in[22];
  float* out = (float*)d_out;
  float* ws  = (float*)d_ws;

  const size_t MC = (size_t)Mm * Cc;
  float* Br   = ws;            // r
  float* Bw   = ws + MC;       // [premix xr] -> w/bb (L3/L4) -> o_pre (epilogue)
  float* Bk   = ws + 2*MC;     // k0 -> kfin
  float* Bkk  = ws + 3*MC;     // [premix xk] -> sv -> law
  float* Bv   = ws + 4*MC;     // v0 -> v
  float* Ba   = ws + 5*MC;     // [premix xv] -> a -> ew
  float* Batt = ws + 6*MC;     // scan output
  float* Bg   = ws + 7*MC;     // g
  float* T1w  = ws + 8*MC;
  float* T1a  = T1w + (size_t)Mm*64;
  float* T1v  = T1a + (size_t)Mm*64;
  float* T1g  = T1v + (size_t)Mm*64;   // Mm*160 floats
  unsigned short* WP = (unsigned short*)(ws + 8*MC + (size_t)Mm*352);
  unsigned short* WrH = WP + 0*(size_t)NPL, *WrL = WP + 1*(size_t)NPL;
  unsigned short* WkH = WP + 2*(size_t)NPL, *WkL = WP + 3*(size_t)NPL;
  unsigned short* WvH = WP + 4*(size_t)NPL, *WvL = WP + 5*(size_t)NPL;
  unsigned short* WoH = WP + 6*(size_t)NPL, *WoL = WP + 7*(size_t)NPL;

  dim3 blk(256,1,1);

  // L0: weight split (W_r, W_k, W_v, W_o -> bf16 hi/lo planes)
  wsplit_kernel<<<dim3(NPL/(256*4),1,4), blk, 0, stream>>>(W_r, W_k, W_v, W_o, WP);

  // L0b: fp32 premix of token-shift inputs (xr -> Bw, xk -> Bkk, xv -> Ba;
  // these buffers are dead until L3 overwrites them)
  premix_kernel<<<dim3(Mm*Cc/(256*4),1,3), blk, 0, stream>>>(hs, xmix, Bw, Bkk, Ba);

  // L1+L2 fused: MFMA projections (384 blocks) || LoRA stage-1 (256 blocks)
  GemmDesc dr{Bw,  W_r, Br, nullptr, Cc, Cc, -1, 0};
  GemmDesc dk{Bkk, W_k, Bk, nullptr, Cc, Cc, -1, 0};
  GemmDesc dv{Ba,  W_v, Bv, nullptr, Cc, Cc, -1, 0};
  GemmDesc s1w{nullptr, w_A, T1w, nullptr, 64, Cc, 1, 1};
  GemmDesc s1a{nullptr, a_A, T1a, nullptr, 64, Cc, 4, 0};
  GemmDesc s1v{nullptr, v_A, T1v, nullptr, 64, Cc, 3, 0};
  GemmDesc s1g{nullptr, g_A, T1g, nullptr, 160, Cc, 5, 2};
  proj_lora_kernel<<<dim3(640,1,1), blk, 0, stream>>>(
      dr, dk, dv, WrH, WrL, WkH, WkL, WvH, WvL,
      s1w, s1a, s1v, s1g, xmix, hs);

  // L3: LoRA stage-2 (overwrites the premix buffers — dead by now)
  GemmDesc s2w{T1w, w_B, Bw,  w_b,    Cc, 64,  -1, 3};
  GemmDesc s2a{T1a, a_B, Ba,  a_b,    Cc, 64,  -1, 2};
  GemmDesc s2v{T1v, v_B, Bkk, v_b,    Cc, 64,  -1, 2};
  GemmDesc s2g{T1g, g_B, Bg,  nullptr,Cc, 160, -1, 0};
  gemm_kernel<<<dim3(8,32,4), blk, 0, stream>>>(s2w,s2a,s2v,s2g, xmix, hs);

  // L4: per-head prep; in place: Bk k0->kfin, Ba a->ew, Bkk sv->law, Bw w->bb, Bv v0->v
  head_prep<<<dim3(Mm*Hh/4), blk, 0, stream>>>(Bk, Ba, Bkk, Bw, Bv,
                                               vfirst, k_k, k_a);

  // L5: sequential scan (v13: 4-deep reg pipeline, counted vmcnt, no barriers)
  scan_kernel<<<dim3(512), dim3(64), 0, stream>>>(Bkk, Ba, Bw, Bk, Br, Bv, Batt);

  // L6: groupnorm + corr + g -> o_pre (reuse Bw; bb dead after scan)
  epilogue_kernel<<<dim3(Mm*Hh/4), blk, 0, stream>>>(Batt, Br, Bk, Bv, Bg,
                                                     r_k, gn_w, gn_b, Bw);

  // L7: output projection via split-bf16 MFMA
  GemmDesc doo{Bw, W_o, out, nullptr, Cc, Cc, -1, 0};
  gemm_mfma<<<dim3(Cc/TN, Mm/TM, 1), blk, 0, stream>>>(
      doo, doo, doo, WoH, WoL, WoH, WoL, WoH, WoL);
}

// Round 14
// 537.585 us; speedup vs baseline: 1.1950x; 1.1950x over previous
//
#include <hip/hip_runtime.h>
#include <math.h>

#define Bb 2
#define Tt 1024
#define Cc 1024
#define Hh 16
#define Dd 64
#define Mm (Bb*Tt)
#define DECAY_SCALE (-0.6065306597126334f)
#define GN_EPS (64e-5f)

typedef __attribute__((ext_vector_type(8))) short short8;   // 8 bf16 (4 VGPRs)
typedef __attribute__((ext_vector_type(4))) float f32x4;    // MFMA acc

struct GemmDesc {
  const float* A;      // used when mixrow < 0 (row stride = K)
  const float* W;      // (N, K) row-major
  float* out;          // (M, N) row-major
  const float* bias;   // per-n bias or nullptr
  int N, K;
  int mixrow;          // >=0: A = token-shift mix of hidden_states with x_mix[mixrow]
  int ep;              // 0 none, 1 tanh, 2 sigmoid(x+bias?), 3 DECAY*sigmoid(x+bias)
};

__device__ __forceinline__ float4 ld4(const float* p){ return *reinterpret_cast<const float4*>(p); }
__device__ __forceinline__ float sigmf(float x){ return 1.f/(1.f+expf(-x)); }

__device__ __forceinline__ float wredsum(float x){
  #pragma unroll
  for (int off=32; off>0; off>>=1) x += __shfl_xor(x, off);
  return x;
}

template<int CTRL>
__device__ __forceinline__ float dppadd(float x){
  return x + __int_as_float(__builtin_amdgcn_update_dpp(0, __float_as_int(x), CTRL, 0xF, 0xF, true));
}

// 16-lane sum (lanes 16k..16k+15), pure DPP (VALU speed, no LDS pipe).
__device__ __forceinline__ float dsum16(float x){
  x = dppadd<0xB1>(x);
  x = dppadd<0x4E>(x);
  x = dppadd<0x141>(x);
  x = dppadd<0x140>(x);
  return x;
}

// two independent 16-lane sums, explicitly interleaved so the second chain's
// DPP latency hides under the first chain's stalls (single-wave in-order issue).
__device__ __forceinline__ void dsum16x2(float& x, float& y){
  x = dppadd<0xB1>(x);  y = dppadd<0xB1>(y);
  x = dppadd<0x4E>(x);  y = dppadd<0x4E>(y);
  x = dppadd<0x141>(x); y = dppadd<0x141>(y);
  x = dppadd<0x140>(x); y = dppadd<0x140>(y);
}

// async global -> LDS DMA (16 B / 4 B per lane); dest = wave-uniform base + lane*size
__device__ __forceinline__ void gl2lds16(const float* g, float* l){
  __builtin_amdgcn_global_load_lds(
      (const __attribute__((address_space(1))) unsigned int*)g,
      (__attribute__((address_space(3))) unsigned int*)l, 16, 0, 0);
}
__device__ __forceinline__ void gl2lds4(const float* g, float* l){
  __builtin_amdgcn_global_load_lds(
      (const __attribute__((address_space(1))) unsigned int*)g,
      (__attribute__((address_space(3))) unsigned int*)l, 4, 0, 0);
}

// split one fp32 value pair into packed bf16 hi/lo words
__device__ __forceinline__ void split2(const float a, const float b,
                                       unsigned& hw, unsigned& lw){
  unsigned u0 = __float_as_uint(a);
  unsigned u1 = __float_as_uint(b);
  float l0 = a - __uint_as_float(u0 & 0xFFFF0000u);
  float l1 = b - __uint_as_float(u1 & 0xFFFF0000u);
  hw = (u0>>16) | (u1 & 0xFFFF0000u);
  lw = (__float_as_uint(l0)>>16) | (__float_as_uint(l1) & 0xFFFF0000u);
}

// ---------------- vector-ALU GEMM (LoRA stages only) ----------------
#define BM 64
#define BN 128
#define BK 32

__global__ __launch_bounds__(256) void gemm_kernel(
    GemmDesc d0, GemmDesc d1, GemmDesc d2, GemmDesc d3,
    const float* __restrict__ xmix, const float* __restrict__ hs)
{
  GemmDesc d = (blockIdx.z==0)?d0:(blockIdx.z==1)?d1:(blockIdx.z==2)?d2:d3;
  const int n0 = blockIdx.x * BN;
  if (n0 >= d.N) return;            // block-uniform
  const int m0 = blockIdx.y * BM;
  const int tid = threadIdx.x;
  __shared__ float As[BK][BM+4];
  __shared__ float Bs[BK][BN+4];
  const int ty = tid >> 4, tx = tid & 15;

  float acc[4][8];
  #pragma unroll
  for (int i=0;i<4;++i)
    #pragma unroll
    for (int j=0;j<8;++j) acc[i][j]=0.f;

  const int K = d.K;
  const int nt = K / BK;
  const float* mrow = (d.mixrow >= 0) ? (xmix + (size_t)d.mixrow * Cc) : nullptr;
  float4 pa[2], pb[4];

  auto load_tile = [&](int kt){
    const int kbase = kt * BK;
    #pragma unroll
    for (int u=0;u<2;++u){
      const int li = tid + u*256;
      const int ar = li >> 3;
      const int kk = ((li & 7) << 2) + kbase;
      const int gm = m0 + ar;
      if (mrow){
        float4 h0 = ld4(hs + (size_t)gm*Cc + kk);
        float4 mx = ld4(mrow + kk);
        float4 hp = make_float4(0.f,0.f,0.f,0.f);
        if ((gm & (Tt-1)) != 0) hp = ld4(hs + (size_t)(gm-1)*Cc + kk);
        pa[u].x = h0.x + (hp.x - h0.x)*mx.x;
        pa[u].y = h0.y + (hp.y - h0.y)*mx.y;
        pa[u].z = h0.z + (hp.z - h0.z)*mx.z;
        pa[u].w = h0.w + (hp.w - h0.w)*mx.w;
      } else {
        pa[u] = ld4(d.A + (size_t)gm*K + kk);
      }
    }
    #pragma unroll
    for (int u=0;u<4;++u){
      const int li = tid + u*256;
      const int br = li >> 3;
      const int kk = ((li & 7) << 2) + kbase;
      const int gn = n0 + br;
      pb[u] = (gn < d.N) ? ld4(d.W + (size_t)gn*K + kk) : make_float4(0.f,0.f,0.f,0.f);
    }
  };

  load_tile(0);
  for (int kt=0; kt<nt; ++kt){
    __syncthreads();
    #pragma unroll
    for (int u=0;u<2;++u){
      const int li = tid + u*256;
      const int ar = li >> 3;
      const int kc = (li & 7) << 2;
      As[kc+0][ar] = pa[u].x; As[kc+1][ar] = pa[u].y;
      As[kc+2][ar] = pa[u].z; As[kc+3][ar] = pa[u].w;
    }
    #pragma unroll
    for (int u=0;u<4;++u){
      const int li = tid + u*256;
      const int br = li >> 3;
      const int kc = (li & 7) << 2;
      Bs[kc+0][br] = pb[u].x; Bs[kc+1][br] = pb[u].y;
      Bs[kc+2][br] = pb[u].z; Bs[kc+3][br] = pb[u].w;
    }
    __syncthreads();
    if (kt+1 < nt) load_tile(kt+1);
    #pragma unroll
    for (int kk=0;kk<BK;++kk){
      const float4 a0 = *(const float4*)&As[kk][ty<<2];
      const float4 b0 = *(const float4*)&Bs[kk][tx<<3];
      const float4 b1 = *(const float4*)&Bs[kk][(tx<<3)+4];
      const float av[4] = {a0.x,a0.y,a0.z,a0.w};
      const float bv[8] = {b0.x,b0.y,b0.z,b0.w,b1.x,b1.y,b1.z,b1.w};
      #pragma unroll
      for (int i=0;i<4;++i)
        #pragma unroll
        for (int j=0;j<8;++j)
          acc[i][j] = fmaf(av[i], bv[j], acc[i][j]);
    }
  }

  const int ep = d.ep;
  #pragma unroll
  for (int i=0;i<4;++i){
    const int gm = m0 + (ty<<2) + i;
    float* orow = d.out + (size_t)gm * d.N;
    #pragma unroll
    for (int j=0;j<8;++j){
      const int gn = n0 + (tx<<3) + j;
      if (gn < d.N){
        float x = acc[i][j];
        if (ep==1) x = tanhf(x);
        else if (ep==2){ if (d.bias) x += d.bias[gn]; x = sigmf(x); }
        else if (ep==3){ x += d.bias[gn]; x = DECAY_SCALE * sigmf(x); }
        orow[gn] = x;
      }
    }
  }
}

// ---------------- weight split pre-pass (fp32 -> bf16 hi/lo planes) ----------------
#define NPL (Cc*Cc)
__global__ __launch_bounds__(256) void wsplit_kernel(
    const float* __restrict__ s0, const float* __restrict__ s1,
    const float* __restrict__ s2, const float* __restrict__ s3,
    unsigned short* __restrict__ planes)
{
  const int z = blockIdx.z;
  const float* src = z==0?s0:z==1?s1:z==2?s2:s3;
  unsigned short* dh = planes + (size_t)z*2*NPL;
  unsigned short* dl = dh + NPL;
  const size_t i = ((size_t)blockIdx.x*256 + threadIdx.x)*4;
  float4 v = ld4(src + i);
  unsigned hw0, lw0, hw1, lw1;
  split2(v.x, v.y, hw0, lw0);
  split2(v.z, v.w, hw1, lw1);
  uint2 hv; hv.x = hw0; hv.y = hw1;
  uint2 lv; lv.x = lw0; lv.y = lw1;
  *(uint2*)(dh + i) = hv;
  *(uint2*)(dl + i) = lv;
}

// ---------------- fp32 premix pre-pass (token-shift mix only, NO split) -----------
__global__ __launch_bounds__(256) void premix_kernel(
    const float* __restrict__ hs, const float* __restrict__ xmix,
    float* __restrict__ p0, float* __restrict__ p1, float* __restrict__ p2)
{
  const int z = blockIdx.z;
  float* ph = z==0?p0:(z==1?p1:p2);
  const int mr = z==0?0:(z==1?2:3);
  const size_t o = ((size_t)blockIdx.x*256 + threadIdx.x)*4;
  const int gm = (int)(o >> 10);          // Cc = 1024
  const int kk = (int)(o & 1023);
  float4 h0 = ld4(hs + o);
  float4 mx = ld4(xmix + (size_t)mr*Cc + kk);
  float4 hp = make_float4(0.f,0.f,0.f,0.f);
  if ((gm & (Tt-1)) != 0) hp = ld4(hs + o - Cc);
  float4 r;
  r.x = h0.x + (hp.x - h0.x)*mx.x;
  r.y = h0.y + (hp.y - h0.y)*mx.y;
  r.z = h0.z + (hp.z - h0.z)*mx.z;
  r.w = h0.w + (hp.w - h0.w)*mx.w;
  *(float4*)(ph + o) = r;
}

// ---------------- split-bf16 MFMA GEMM (big projections) ----------------
// v4: W-plane staging via global_load_lds DMA (m97 recipe). B path per K-step:
// 4 DMA issues/thread replace 8 uint4 loads + 8 ds_write_b128. B is packed
// [128 rows][32 kshorts] per plane, double-buffered (DMA for kt+1 in flight
// under kt's MFMA; one vmcnt(0) per step, covered by the MFMA phase).
// Linear-dest DMA forces the swizzle to live in the SOURCE address (m173/T2):
// kbyte ^= ((row>>1)&3)<<4 on both the per-lane global source and the
// fragment read -> verified 2-way bank access (free per m136). A path
// (premix fp32, in-loop split2, LDBS=40 pad) unchanged -> bit-identical math.
#define TM 128
#define TN 128
#define LDBS 40   // bf16 row stride in LDS (A planes)

__global__ __launch_bounds__(256) void gemm_mfma(
    GemmDesc d0, GemmDesc d1, GemmDesc d2,
    const unsigned short* __restrict__ WH0, const unsigned short* __restrict__ WL0,
    const unsigned short* __restrict__ WH1, const unsigned short* __restrict__ WL1,
    const unsigned short* __restrict__ WH2, const unsigned short* __restrict__ WL2)
{
  const int z = blockIdx.z;
  GemmDesc d = z==0?d0:(z==1?d1:d2);
  const unsigned short* WH = z==0?WH0:(z==1?WH1:WH2);
  const unsigned short* WL = z==0?WL0:(z==1?WL1:WL2);
  const int m0 = blockIdx.y * TM;
  const int n0 = blockIdx.x * TN;
  const int K  = d.K;
  const int tid = threadIdx.x;

  __shared__ __align__(16) unsigned short Ah[TM*LDBS], Al[TM*LDBS];
  __shared__ __align__(16) unsigned short Bh[2][TN*32], Bl[2][TN*32];

  const int sr = tid >> 1;
  const int sk = (tid & 1) << 4;
  const int gmA = m0 + sr;
  const int wv = tid >> 6, lane = tid & 63;

  float4 pa[4];
  auto load_A = [&](int kt){
    const int kb = kt*32 + sk;
    #pragma unroll
    for (int u=0;u<4;++u)
      pa[u] = ld4(d.A + (size_t)gmA*K + kb + 4*u);
  };
  // DMA-stage one 128x32 bf16 slab per plane. Wave wv covers rows 32wv..32wv+31;
  // call c covers rows 32wv+16c..+16. Lane L -> dest byte (wave base)+c*1024+L*16
  // = row 32wv+16c+(L>>2), stored kbyte (L&3)*16. Source reads the LOGICAL kbyte
  // stored there: ((L&3) ^ ((rl>>1)&3))<<4  (XOR-swizzle in the source address).
  auto stage_B = [&](int kt, int buf){
    #pragma unroll
    for (int c=0;c<2;++c){
      const int rl  = (c<<4) + (lane>>2);          // row within wave slab, 0..31
      const int row = (wv<<5) + rl;
      const unsigned lk = (unsigned)(((lane&3) ^ ((rl>>1)&3)) << 4);  // logical kbyte
      const size_t gb = (((size_t)(n0 + row)*K + kt*32) << 1) + lk;   // byte offset
      char* db = (char*)(&Bh[buf][0]) + (wv<<11) + (c<<10);           // wave-uniform
      gl2lds16((const float*)((const char*)WH + gb), (float*)db);
      char* dl = (char*)(&Bl[buf][0]) + (wv<<11) + (c<<10);
      gl2lds16((const float*)((const char*)WL + gb), (float*)dl);
    }
  };

  const int wm = (wv >> 1) << 6, wn = (wv & 1) << 6;
  const int fr = lane & 15;
  const int fk = (lane >> 4) << 3;

  f32x4 acc[4][4];
  const f32x4 z4 = {0.f,0.f,0.f,0.f};
  #pragma unroll
  for (int i=0;i<4;++i)
    #pragma unroll
    for (int j=0;j<4;++j) acc[i][j]=z4;

  const int nslab = K >> 5;
  load_A(0);
  stage_B(0, 0);
  for (int kt=0; kt<nslab; ++kt){
    __syncthreads();                       // prior MFMA reads of Ah/Al done
    {
      unsigned hw[8], lw[8];
      #pragma unroll
      for (int u=0;u<4;++u){
        const float xs[4] = {pa[u].x, pa[u].y, pa[u].z, pa[u].w};
        split2(xs[0], xs[1], hw[u*2+0], lw[u*2+0]);
        split2(xs[2], xs[3], hw[u*2+1], lw[u*2+1]);
      }
      uint4 t;
      t.x=hw[0];t.y=hw[1];t.z=hw[2];t.w=hw[3]; *(uint4*)&Ah[sr*LDBS+sk]   = t;
      t.x=hw[4];t.y=hw[5];t.z=hw[6];t.w=hw[7]; *(uint4*)&Ah[sr*LDBS+sk+8] = t;
      t.x=lw[0];t.y=lw[1];t.z=lw[2];t.w=lw[3]; *(uint4*)&Al[sr*LDBS+sk]   = t;
      t.x=lw[4];t.y=lw[5];t.z=lw[6];t.w=lw[7]; *(uint4*)&Al[sr*LDBS+sk+8] = t;
    }
    __builtin_amdgcn_s_waitcnt(0x0F70);    // vmcnt(0): this tile's B-DMA landed
    __syncthreads();
    if (kt+1 < nslab){ load_A(kt+1); stage_B(kt+1, (kt+1)&1); }

    const unsigned short* BhT = &Bh[kt&1][0];
    const unsigned short* BlT = &Bl[kt&1][0];
    short8 bh4[4], bl4[4];
    #pragma unroll
    for (int nt=0;nt<4;++nt){
      const int rowB = wn + nt*16 + fr;
      const int so = rowB*32 + (fk ^ (((rowB>>1)&3)<<3));   // swizzled read
      bh4[nt] = *(const short8*)&BhT[so];
      bl4[nt] = *(const short8*)&BlT[so];
    }
    #pragma unroll
    for (int mt=0;mt<4;++mt){
      const short8 ah = *(const short8*)&Ah[(wm + mt*16 + fr)*LDBS + fk];
      const short8 al = *(const short8*)&Al[(wm + mt*16 + fr)*LDBS + fk];
      #pragma unroll
      for (int nt=0;nt<4;++nt)
        acc[mt][nt] = __builtin_amdgcn_mfma_f32_16x16x32_bf16(ah, bh4[nt], acc[mt][nt], 0,0,0);
      #pragma unroll
      for (int nt=0;nt<4;++nt)
        acc[mt][nt] = __builtin_amdgcn_mfma_f32_16x16x32_bf16(ah, bl4[nt], acc[mt][nt], 0,0,0);
      #pragma unroll
      for (int nt=0;nt<4;++nt)
        acc[mt][nt] = __builtin_amdgcn_mfma_f32_16x16x32_bf16(al, bh4[nt], acc[mt][nt], 0,0,0);
    }
  }

  #pragma unroll
  for (int mt=0;mt<4;++mt){
    #pragma unroll
    for (int nt=0;nt<4;++nt){
      #pragma unroll
      for (int r=0;r<4;++r){
        const int row = wm + mt*16 + ((lane>>4)<<2) + r;
        const int col = wn + nt*16 + fr;
        d.out[(size_t)(m0+row)*d.N + n0 + col] = acc[mt][nt][r];
      }
    }
  }
}

// ---------------- per-head prep (in-place coefficient precompute) ----------------
__global__ __launch_bounds__(256) void head_prep(
    float* kbuf, float* awbuf, float* svwbuf, float* wbbuf, float* vbuf,
    const float* __restrict__ vfirst,
    const float* __restrict__ k_k, const float* __restrict__ k_a)
{
  const int gid = blockIdx.x*4 + (threadIdx.x>>6);
  const int e = threadIdx.x & 63;
  const int m = gid >> 4;
  const int h = gid & 15;
  const int c = h*Dd + e;
  const size_t idx = (size_t)m*Cc + c;
  const float kv0 = kbuf[idx];
  const float av  = awbuf[idx];
  const float sv  = svwbuf[idx];
  const float wv  = wbbuf[idx];
  const float v0  = vbuf[idx];
  const float vf  = vfirst[idx];
  const float kku = kv0 * k_k[c];
  const float ss  = wredsum(kku*kku);
  const float kkn = kku / fmaxf(sqrtf(ss), 1e-12f);
  const float ew  = expf(wv);
  kbuf[idx]  = kv0 * (1.f + (av - 1.f)*k_a[c]);
  awbuf[idx] = ew;
  svwbuf[idx]= -kkn * ew;
  wbbuf[idx] = kkn * av;
  vbuf[idx]  = v0 + sv*(vf - v0);
}

// ---------------- sequential scan v13: 4-deep register pipeline + counted vmcnt ----
#define NB (Tt/16)
struct Coef { float4 Lw, Ew, Bq, Kq, Rq; float Vv; };
__global__ __launch_bounds__(64) void scan_kernel(
    const float* __restrict__ lawb, const float* __restrict__ ewb,
    const float* __restrict__ bbb,  const float* __restrict__ kb,
    const float* __restrict__ rb,   const float* __restrict__ vb,
    float* __restrict__ outp)
{
  const int blk  = blockIdx.x;
  const int bh   = blk & 31;        // chain id; 16 blocks %32-congruent -> same XCD
  const int blkc = blk >> 5;        // 0..15: column quad
  const int b = bh >> 4, h = bh & 15;
  const int lane = threadIdx.x;
  const int es = lane >> 4;         // column slot 0..3
  const int rd = lane & 15;         // row quad (rows 4rd..4rd+3)
  const int colb = blkc * 4;
  const int hb = h * Dd;
  const int la = 4*rd;              // dword offset of this lane's row quad

  // per buffer: law[1024] ew[1024] bb[1024] k[1024] r[1024] v[64]
  __shared__ __align__(16) float LB[2][5*1024 + 64];

  float S0=0.f, S1=0.f, S2=0.f, S3=0.f;
  float4 Rp = make_float4(0.f,0.f,0.f,0.f);   // r of previous step (r_{g-1})
  const size_t mbase = (size_t)b*Tt;
  float* ocol = outp + mbase*Cc + hb + colb + es;   // column base for rd==0 stores

  const int qrow = lane >> 4;           // staging: row within 4-row slab
  const int qcol = (lane & 15) * 4;     // staging: dword col

  auto stage = [&](int bt){
    const size_t g0 = (mbase + (size_t)bt*16)*Cc + hb;
    float* dst = &LB[bt&1][0];
    const float* srcs[5] = {lawb, ewb, bbb, kb, rb};
    #pragma unroll
    for (int a=0;a<5;++a){
      const float* s = srcs[a] + g0 + (size_t)qrow*Cc + qcol;
      #pragma unroll
      for (int i=0;i<4;++i)
        gl2lds16(s + (size_t)(4*i)*Cc, dst + a*1024 + i*256);
    }
    gl2lds4(vb + g0 + (size_t)(lane>>2)*Cc + colb + (lane&3), dst + 5120);
  };

  stage(0);
  __builtin_amdgcn_s_waitcnt(0x0F70);   // vmcnt(0): batch 0's DMA complete

  for (int bt = 0; bt < NB; ++bt){
    if (bt+1 < NB) stage(bt+1);           // in flight under this batch's compute
    const float* cb2 = &LB[bt&1][0];

    auto ldq = [&](int t, Coef& c){
      c.Lw = *(const float4*)&cb2[         t*64 + la];
      c.Ew = *(const float4*)&cb2[1024 + t*64 + la];
      c.Bq = *(const float4*)&cb2[2048 + t*64 + la];
      c.Kq = *(const float4*)&cb2[3072 + t*64 + la];
      c.Rq = *(const float4*)&cb2[4096 + t*64 + la];
      c.Vv = cb2[5120 + t*4 + es];
    };

    Coef cA, cB, cC, cD;
    ldq(0, cA); ldq(1, cB); ldq(2, cC); ldq(3, cD);

    auto stepf = [&](int t, Coef& c){
      const float4 Lw = c.Lw, Ew = c.Ew, Bq = c.Bq, Kq = c.Kq, rr = c.Rq;
      const float vv = c.Vv;
      // both dots read S_old: ta for THIS step's update, op for PREVIOUS step's output
      float tp = fmaf(Lw.y, S1, Lw.x*S0);
      float tb = fmaf(Lw.w, S3, Lw.z*S2);
      tp += tb;
      float op = fmaf(Rp.y, S1, Rp.x*S0);
      float ob = fmaf(Rp.w, S3, Rp.z*S2);
      op += ob;
      dsum16x2(tp, op);                       // interleaved: op hides under tp's chain
      // store out(g-1); only batch 0 / t==0 has no predecessor
      const bool gv = (bt > 0) | (t > 0);
      if (gv && rd == 0)
        ocol[(size_t)(bt*16 + t - 1)*Cc] = op;
      S0 = fmaf(Ew.x, S0, fmaf(Bq.x, tp, Kq.x*vv));
      S1 = fmaf(Ew.y, S1, fmaf(Bq.y, tp, Kq.y*vv));
      S2 = fmaf(Ew.z, S2, fmaf(Bq.z, tp, Kq.z*vv));
      S3 = fmaf(Ew.w, S3, fmaf(Bq.w, tp, Kq.w*vv));
      Rp = rr;                                // r_g becomes r_{g-1} for next step
      if (t+4 < 16) ldq(t+4, c);              // refill same buffer, 4 steps ahead
    };

    #pragma unroll
    for (int t = 0; t < 16; ++t){
      const int s = t & 3;
      if      (s == 0) stepf(t, cA);
      else if (s == 1) stepf(t, cB);
      else if (s == 2) stepf(t, cC);
      else             stepf(t, cD);
    }

    // counted wait: stage(bt+1)'s 22 DMA ops are the OLDEST outstanding vm ops;
    // <=16 output stores were issued after them. vmcnt(16) => all DMA landed.
    if (bt+1 < NB) __builtin_amdgcn_s_waitcnt(0x4F70);   // vmcnt(16)
  }

  // flush: out(T-1) = r_{T-1} . S(T-1)
  {
    float op = fmaf(Rp.y, S1, Rp.x*S0);
    float ob = fmaf(Rp.w, S3, Rp.z*S2);
    op = dsum16(op + ob);
    if (rd == 0)
      ocol[(size_t)(Tt - 1)*Cc] = op;
  }
}

// ---------------- GroupNorm + correction + g gating ----------------
__global__ __launch_bounds__(256) void epilogue_kernel(
    const float* __restrict__ att, const float* __restrict__ rbuf,
    const float* __restrict__ kbuf, const float* __restrict__ vbuf,
    const float* __restrict__ gbuf,
    const float* __restrict__ r_k, const float* __restrict__ gn_w,
    const float* __restrict__ gn_b, float* __restrict__ opre)
{
  const int gid = blockIdx.x*4 + (threadIdx.x>>6);
  const int e = threadIdx.x & 63;
  const int m = gid >> 4;
  const int h = gid & 15;
  const int c = h*Dd + e;
  const size_t idx = (size_t)m*Cc + c;
  const float x  = att[idx];
  const float mu = wredsum(x) * (1.f/Dd);
  const float xd = x - mu;
  const float var = wredsum(xd*xd) * (1.f/Dd);
  const float og = xd * (1.f/sqrtf(var + GN_EPS)) * gn_w[c] + gn_b[c];
  const float rv = rbuf[idx], kv = kbuf[idx], vv = vbuf[idx];
  const float cd = wredsum(rv*kv*r_k[c]);
  opre[idx] = (og + cd*vv) * gbuf[idx];
}

extern "C" void kernel_launch(void* const* d_in, const int* in_sizes, int n_in,
                              void* d_out, int out_size, void* d_ws, size_t ws_size,
                              hipStream_t stream)
{
  (void)in_sizes; (void)n_in; (void)out_size; (void)ws_size;
  const float* hs     = (const float*)d_in[0];
  const float* vfirst = (const float*)d_in[1];
  const float* xmix   = (const float*)d_in[2];
  const float* k_k    = (const float*)d_in[3];
  const float* k_a    = (const float*)d_in[4];
  const float* r_k    = (const float*)d_in[5];
  const float* W_r    = (const float*)d_in[6];
  const float* W_k    = (const float*)d_in[7];
  const float* W_v    = (const float*)d_in[8];
  const float* W_o    = (const float*)d_in[9];
  const float* w_A    = (const float*)d_in[10];
  const float* w_B    = (const float*)d_in[11];
  const float* w_b    = (const float*)d_in[12];
  const float* a_A    = (const float*)d_in[13];
  const float* a_B    = (const float*)d_in[14];
  const float* a_b    = (const float*)d_in[15];
  const float* v_A    = (const float*)d_in[16];
  const float* v_B    = (const float*)d_in[17];
  const float* v_b    = (const float*)d_in[18];
  const float* g_A    = (const float*)d_in[19];
  const float* g_B    = (const float*)d_in[20];
  const float* gn_w   = (const float*)d_in[21];
  const float* gn_b   = (const float*)d_in[22];
  float* out = (float*)d_out;
  float* ws  = (float*)d_ws;

  const size_t MC = (size_t)Mm * Cc;
  float* Br   = ws;            // r
  float* Bw   = ws + MC;       // [premix xr] -> w/bb (L3/L4) -> o_pre (epilogue)
  float* Bk   = ws + 2*MC;     // k0 -> kfin
  float* Bkk  = ws + 3*MC;     // [premix xk] -> sv -> law
  float* Bv   = ws + 4*MC;     // v0 -> v
  float* Ba   = ws + 5*MC;     // [premix xv] -> a -> ew
  float* Batt = ws + 6*MC;     // scan output
  float* Bg   = ws + 7*MC;     // g
  float* T1w  = ws + 8*MC;
  float* T1a  = T1w + (size_t)Mm*64;
  float* T1v  = T1a + (size_t)Mm*64;
  float* T1g  = T1v + (size_t)Mm*64;   // Mm*160 floats
  unsigned short* WP = (unsigned short*)(ws + 8*MC + (size_t)Mm*352);
  unsigned short* WrH = WP + 0*(size_t)NPL, *WrL = WP + 1*(size_t)NPL;
  unsigned short* WkH = WP + 2*(size_t)NPL, *WkL = WP + 3*(size_t)NPL;
  unsigned short* WvH = WP + 4*(size_t)NPL, *WvL = WP + 5*(size_t)NPL;
  unsigned short* WoH = WP + 6*(size_t)NPL, *WoL = WP + 7*(size_t)NPL;

  dim3 blk(256,1,1);

  // L0: weight split (W_r, W_k, W_v, W_o -> bf16 hi/lo planes)
  wsplit_kernel<<<dim3(NPL/(256*4),1,4), blk, 0, stream>>>(W_r, W_k, W_v, W_o, WP);

  // L0b: fp32 premix of token-shift inputs (xr -> Bw, xk -> Bkk, xv -> Ba;
  // these buffers are dead until L3 overwrites them)
  premix_kernel<<<dim3(Mm*Cc/(256*4),1,3), blk, 0, stream>>>(hs, xmix, Bw, Bkk, Ba);

  // L1: big projections r, k0, v0 via split-bf16 MFMA (premixed fp32 A, DMA B)
  GemmDesc dr{Bw,  W_r, Br, nullptr, Cc, Cc, -1, 0};
  GemmDesc dk{Bkk, W_k, Bk, nullptr, Cc, Cc, -1, 0};
  GemmDesc dv{Ba,  W_v, Bv, nullptr, Cc, Cc, -1, 0};
  gemm_mfma<<<dim3(Cc/TN, Mm/TM, 3), blk, 0, stream>>>(
      dr, dk, dv, WrH, WrL, WkH, WkL, WvH, WvL);

  // L2: LoRA stage-1 (w: tanh; a: none; v: none; g: sigmoid)
  GemmDesc s1w{nullptr, w_A, T1w, nullptr, 64, Cc, 1, 1};
  GemmDesc s1a{nullptr, a_A, T1a, nullptr, 64, Cc, 4, 0};
  GemmDesc s1v{nullptr, v_A, T1v, nullptr, 64, Cc, 3, 0};
  GemmDesc s1g{nullptr, g_A, T1g, nullptr, 160, Cc, 5, 2};
  gemm_kernel<<<dim3(2,32,4), blk, 0, stream>>>(s1w,s1a,s1v,s1g, xmix, hs);

  // L3: LoRA stage-2 (overwrites the premix buffers — dead by now)
  GemmDesc s2w{T1w, w_B, Bw,  w_b,    Cc, 64,  -1, 3};
  GemmDesc s2a{T1a, a_B, Ba,  a_b,    Cc, 64,  -1, 2};
  GemmDesc s2v{T1v, v_B, Bkk, v_b,    Cc, 64,  -1, 2};
  GemmDesc s2g{T1g, g_B, Bg,  nullptr,Cc, 160, -1, 0};
  gemm_kernel<<<dim3(8,32,4), blk, 0, stream>>>(s2w,s2a,s2v,s2g, xmix, hs);

  // L4: per-head prep; in place: Bk k0->kfin, Ba a->ew, Bkk sv->law, Bw w->bb, Bv v0->v
  head_prep<<<dim3(Mm*Hh/4), blk, 0, stream>>>(Bk, Ba, Bkk, Bw, Bv,
                                               vfirst, k_k, k_a);

  // L5: sequential scan (v13: 4-deep reg pipeline, counted vmcnt, no barriers)
  scan_kernel<<<dim3(512), dim3(64), 0, stream>>>(Bkk, Ba, Bw, Bk, Br, Bv, Batt);

  // L6: groupnorm + corr + g -> o_pre (reuse Bw; bb dead after scan)
  epilogue_kernel<<<dim3(Mm*Hh/4), blk, 0, stream>>>(Batt, Br, Bk, Bv, Bg,
                                                     r_k, gn_w, gn_b, Bw);

  // L7: output projection via split-bf16 MFMA
  GemmDesc doo{Bw, W_o, out, nullptr, Cc, Cc, -1, 0};
  gemm_mfma<<<dim3(Cc/TN, Mm/TM, 1), blk, 0, stream>>>(
      doo, doo, doo, WoH, WoL, WoH, WoL, WoH, WoL);
}

// Round 15
// 517.716 us; speedup vs baseline: 1.2408x; 1.0384x over previous
//
#include <hip/hip_runtime.h>
#include <math.h>

#define Bb 2
#define Tt 1024
#define Cc 1024
#define Hh 16
#define Dd 64
#define Mm (Bb*Tt)
#define DECAY_SCALE (-0.6065306597126334f)
#define GN_EPS (64e-5f)

typedef __attribute__((ext_vector_type(8))) short short8;   // 8 bf16 (4 VGPRs)
typedef __attribute__((ext_vector_type(4))) float f32x4;    // MFMA acc

struct GemmDesc {
  const float* A;      // used when mixrow < 0 (row stride = K)
  const float* W;      // (N, K) row-major
  float* out;          // (M, N) row-major
  const float* bias;   // per-n bias or nullptr
  int N, K;
  int mixrow;          // >=0: A = token-shift mix of hidden_states with x_mix[mixrow]
  int ep;              // 0 none, 1 tanh, 2 sigmoid(x+bias?), 3 DECAY*sigmoid(x+bias)
};

__device__ __forceinline__ float4 ld4(const float* p){ return *reinterpret_cast<const float4*>(p); }
__device__ __forceinline__ float sigmf(float x){ return 1.f/(1.f+expf(-x)); }

__device__ __forceinline__ float wredsum(float x){
  #pragma unroll
  for (int off=32; off>0; off>>=1) x += __shfl_xor(x, off);
  return x;
}

template<int CTRL>
__device__ __forceinline__ float dppadd(float x){
  return x + __int_as_float(__builtin_amdgcn_update_dpp(0, __float_as_int(x), CTRL, 0xF, 0xF, true));
}

// 16-lane sum (lanes 16k..16k+15), pure DPP (VALU speed, no LDS pipe).
__device__ __forceinline__ float dsum16(float x){
  x = dppadd<0xB1>(x);
  x = dppadd<0x4E>(x);
  x = dppadd<0x141>(x);
  x = dppadd<0x140>(x);
  return x;
}

// two independent 16-lane sums, explicitly interleaved so the second chain's
// DPP latency hides under the first chain's stalls (single-wave in-order issue).
__device__ __forceinline__ void dsum16x2(float& x, float& y){
  x = dppadd<0xB1>(x);  y = dppadd<0xB1>(y);
  x = dppadd<0x4E>(x);  y = dppadd<0x4E>(y);
  x = dppadd<0x141>(x); y = dppadd<0x141>(y);
  x = dppadd<0x140>(x); y = dppadd<0x140>(y);
}

// async global -> LDS DMA (16 B / 4 B per lane); dest = wave-uniform base + lane*size
__device__ __forceinline__ void gl2lds16(const float* g, float* l){
  __builtin_amdgcn_global_load_lds(
      (const __attribute__((address_space(1))) unsigned int*)g,
      (__attribute__((address_space(3))) unsigned int*)l, 16, 0, 0);
}
__device__ __forceinline__ void gl2lds4(const float* g, float* l){
  __builtin_amdgcn_global_load_lds(
      (const __attribute__((address_space(1))) unsigned int*)g,
      (__attribute__((address_space(3))) unsigned int*)l, 4, 0, 0);
}

// split one fp32 value pair into packed bf16 hi/lo words
__device__ __forceinline__ void split2(const float a, const float b,
                                       unsigned& hw, unsigned& lw){
  unsigned u0 = __float_as_uint(a);
  unsigned u1 = __float_as_uint(b);
  float l0 = a - __uint_as_float(u0 & 0xFFFF0000u);
  float l1 = b - __uint_as_float(u1 & 0xFFFF0000u);
  hw = (u0>>16) | (u1 & 0xFFFF0000u);
  lw = (__float_as_uint(l0)>>16) | (__float_as_uint(l1) & 0xFFFF0000u);
}

#define BM 64
#define BN 128
#define BK 32

// ---------------- vector-ALU GEMM (LoRA stage-2) ----------------
__global__ __launch_bounds__(256) void gemm_kernel(
    GemmDesc d0, GemmDesc d1, GemmDesc d2, GemmDesc d3,
    const float* __restrict__ xmix, const float* __restrict__ hs)
{
  GemmDesc d = (blockIdx.z==0)?d0:(blockIdx.z==1)?d1:(blockIdx.z==2)?d2:d3;
  const int n0 = blockIdx.x * BN;
  if (n0 >= d.N) return;            // block-uniform
  const int m0 = blockIdx.y * BM;
  const int tid = threadIdx.x;
  __shared__ float As[BK][BM+4];
  __shared__ float Bs[BK][BN+4];
  const int ty = tid >> 4, tx = tid & 15;

  float acc[4][8];
  #pragma unroll
  for (int i=0;i<4;++i)
    #pragma unroll
    for (int j=0;j<8;++j) acc[i][j]=0.f;

  const int K = d.K;
  const int nt = K / BK;
  const float* mrow = (d.mixrow >= 0) ? (xmix + (size_t)d.mixrow * Cc) : nullptr;
  float4 pa[2], pb[4];

  auto load_tile = [&](int kt){
    const int kbase = kt * BK;
    #pragma unroll
    for (int u=0;u<2;++u){
      const int li = tid + u*256;
      const int ar = li >> 3;
      const int kk = ((li & 7) << 2) + kbase;
      const int gm = m0 + ar;
      if (mrow){
        float4 h0 = ld4(hs + (size_t)gm*Cc + kk);
        float4 mx = ld4(mrow + kk);
        float4 hp = make_float4(0.f,0.f,0.f,0.f);
        if ((gm & (Tt-1)) != 0) hp = ld4(hs + (size_t)(gm-1)*Cc + kk);
        pa[u].x = h0.x + (hp.x - h0.x)*mx.x;
        pa[u].y = h0.y + (hp.y - h0.y)*mx.y;
        pa[u].z = h0.z + (hp.z - h0.z)*mx.z;
        pa[u].w = h0.w + (hp.w - h0.w)*mx.w;
      } else {
        pa[u] = ld4(d.A + (size_t)gm*K + kk);
      }
    }
    #pragma unroll
    for (int u=0;u<4;++u){
      const int li = tid + u*256;
      const int br = li >> 3;
      const int kk = ((li & 7) << 2) + kbase;
      const int gn = n0 + br;
      pb[u] = (gn < d.N) ? ld4(d.W + (size_t)gn*K + kk) : make_float4(0.f,0.f,0.f,0.f);
    }
  };

  load_tile(0);
  for (int kt=0; kt<nt; ++kt){
    __syncthreads();
    #pragma unroll
    for (int u=0;u<2;++u){
      const int li = tid + u*256;
      const int ar = li >> 3;
      const int kc = (li & 7) << 2;
      As[kc+0][ar] = pa[u].x; As[kc+1][ar] = pa[u].y;
      As[kc+2][ar] = pa[u].z; As[kc+3][ar] = pa[u].w;
    }
    #pragma unroll
    for (int u=0;u<4;++u){
      const int li = tid + u*256;
      const int br = li >> 3;
      const int kc = (li & 7) << 2;
      Bs[kc+0][br] = pb[u].x; Bs[kc+1][br] = pb[u].y;
      Bs[kc+2][br] = pb[u].z; Bs[kc+3][br] = pb[u].w;
    }
    __syncthreads();
    if (kt+1 < nt) load_tile(kt+1);
    #pragma unroll
    for (int kk=0;kk<BK;++kk){
      const float4 a0 = *(const float4*)&As[kk][ty<<2];
      const float4 b0 = *(const float4*)&Bs[kk][tx<<3];
      const float4 b1 = *(const float4*)&Bs[kk][(tx<<3)+4];
      const float av[4] = {a0.x,a0.y,a0.z,a0.w};
      const float bv[8] = {b0.x,b0.y,b0.z,b0.w,b1.x,b1.y,b1.z,b1.w};
      #pragma unroll
      for (int i=0;i<4;++i)
        #pragma unroll
        for (int j=0;j<8;++j)
          acc[i][j] = fmaf(av[i], bv[j], acc[i][j]);
    }
  }

  const int ep = d.ep;
  #pragma unroll
  for (int i=0;i<4;++i){
    const int gm = m0 + (ty<<2) + i;
    float* orow = d.out + (size_t)gm * d.N;
    #pragma unroll
    for (int j=0;j<8;++j){
      const int gn = n0 + (tx<<3) + j;
      if (gn < d.N){
        float x = acc[i][j];
        if (ep==1) x = tanhf(x);
        else if (ep==2){ if (d.bias) x += d.bias[gn]; x = sigmf(x); }
        else if (ep==3){ x += d.bias[gn]; x = DECAY_SCALE * sigmf(x); }
        orow[gn] = x;
      }
    }
  }
}

// ---------------- LoRA stage-1: N=64 slices on a BN=64 tile (z<3) + g (z==3) ------
// z<3 (w/a/v, N=64): 64x64 tile, thread = 4 rows x 4 cols -> HALF the FMA of the
// BN=128 kernel (whose tx>=8 columns were discarded by the store guard). Same
// k-accumulation order per output element -> bit-identical. z==3 (g, N=160):
// original BN=128 body.
__global__ __launch_bounds__(256) void lora1_kernel(
    GemmDesc e0, GemmDesc e1, GemmDesc e2, GemmDesc e3,
    const float* __restrict__ xmix, const float* __restrict__ hs)
{
  __shared__ __align__(16) unsigned char SMEM[25600];
  const int z = blockIdx.z;
  const int tid = threadIdx.x;

  if (z < 3){
    if (blockIdx.x != 0) return;
    GemmDesc d = (z==0)?e0:(z==1)?e1:e2;
    const int m0 = blockIdx.y * BM;
    float (*As)[BM+4] = reinterpret_cast<float(*)[BM+4]>(SMEM);
    float (*Bs)[BM+4] = reinterpret_cast<float(*)[BM+4]>(SMEM + sizeof(float)*BK*(BM+4));
    const int ty = tid >> 4, tx = tid & 15;

    float acc[4][4];
    #pragma unroll
    for (int i=0;i<4;++i)
      #pragma unroll
      for (int j=0;j<4;++j) acc[i][j]=0.f;

    const int K = d.K;
    const int nt = K / BK;
    const float* mrow = xmix + (size_t)d.mixrow * Cc;
    float4 pa[2], pb[2];

    auto load_tile = [&](int kt){
      const int kbase = kt * BK;
      #pragma unroll
      for (int u=0;u<2;++u){
        const int li = tid + u*256;
        const int ar = li >> 3;
        const int kk = ((li & 7) << 2) + kbase;
        const int gm = m0 + ar;
        float4 h0 = ld4(hs + (size_t)gm*Cc + kk);
        float4 mx = ld4(mrow + kk);
        float4 hp = make_float4(0.f,0.f,0.f,0.f);
        if ((gm & (Tt-1)) != 0) hp = ld4(hs + (size_t)(gm-1)*Cc + kk);
        pa[u].x = h0.x + (hp.x - h0.x)*mx.x;
        pa[u].y = h0.y + (hp.y - h0.y)*mx.y;
        pa[u].z = h0.z + (hp.z - h0.z)*mx.z;
        pa[u].w = h0.w + (hp.w - h0.w)*mx.w;
        pb[u] = ld4(d.W + (size_t)ar*K + kk);
      }
    };

    load_tile(0);
    for (int kt=0; kt<nt; ++kt){
      __syncthreads();
      #pragma unroll
      for (int u=0;u<2;++u){
        const int li = tid + u*256;
        const int ar = li >> 3;
        const int kc = (li & 7) << 2;
        As[kc+0][ar] = pa[u].x; As[kc+1][ar] = pa[u].y;
        As[kc+2][ar] = pa[u].z; As[kc+3][ar] = pa[u].w;
        Bs[kc+0][ar] = pb[u].x; Bs[kc+1][ar] = pb[u].y;
        Bs[kc+2][ar] = pb[u].z; Bs[kc+3][ar] = pb[u].w;
      }
      __syncthreads();
      if (kt+1 < nt) load_tile(kt+1);
      #pragma unroll
      for (int kk=0;kk<BK;++kk){
        const float4 a0 = *(const float4*)&As[kk][ty<<2];
        const float4 b0 = *(const float4*)&Bs[kk][tx<<2];
        const float av[4] = {a0.x,a0.y,a0.z,a0.w};
        const float bv[4] = {b0.x,b0.y,b0.z,b0.w};
        #pragma unroll
        for (int i=0;i<4;++i)
          #pragma unroll
          for (int j=0;j<4;++j)
            acc[i][j] = fmaf(av[i], bv[j], acc[i][j]);
      }
    }

    const int ep = d.ep;
    #pragma unroll
    for (int i=0;i<4;++i){
      const int gm = m0 + (ty<<2) + i;
      float* orow = d.out + (size_t)gm * d.N;
      #pragma unroll
      for (int j=0;j<4;++j){
        const int gn = (tx<<2) + j;
        float x = acc[i][j];
        if (ep==1) x = tanhf(x);
        orow[gn] = x;
      }
    }
  } else {
    // g slice (N=160): BN=128 body
    GemmDesc d = e3;
    const int n0 = blockIdx.x * BN;
    if (n0 >= d.N) return;
    const int m0 = blockIdx.y * BM;
    float (*As)[BM+4] = reinterpret_cast<float(*)[BM+4]>(SMEM);
    float (*Bs)[BN+4] = reinterpret_cast<float(*)[BN+4]>(SMEM + sizeof(float)*BK*(BM+4));
    const int ty = tid >> 4, tx = tid & 15;

    float acc[4][8];
    #pragma unroll
    for (int i=0;i<4;++i)
      #pragma unroll
      for (int j=0;j<8;++j) acc[i][j]=0.f;

    const int K = d.K;
    const int nt = K / BK;
    const float* mrow = xmix + (size_t)d.mixrow * Cc;
    float4 pa[2], pb[4];

    auto load_tile = [&](int kt){
      const int kbase = kt * BK;
      #pragma unroll
      for (int u=0;u<2;++u){
        const int li = tid + u*256;
        const int ar = li >> 3;
        const int kk = ((li & 7) << 2) + kbase;
        const int gm = m0 + ar;
        float4 h0 = ld4(hs + (size_t)gm*Cc + kk);
        float4 mx = ld4(mrow + kk);
        float4 hp = make_float4(0.f,0.f,0.f,0.f);
        if ((gm & (Tt-1)) != 0) hp = ld4(hs + (size_t)(gm-1)*Cc + kk);
        pa[u].x = h0.x + (hp.x - h0.x)*mx.x;
        pa[u].y = h0.y + (hp.y - h0.y)*mx.y;
        pa[u].z = h0.z + (hp.z - h0.z)*mx.z;
        pa[u].w = h0.w + (hp.w - h0.w)*mx.w;
      }
      #pragma unroll
      for (int u=0;u<4;++u){
        const int li = tid + u*256;
        const int br = li >> 3;
        const int kk = ((li & 7) << 2) + kbase;
        const int gn = n0 + br;
        pb[u] = (gn < d.N) ? ld4(d.W + (size_t)gn*K + kk) : make_float4(0.f,0.f,0.f,0.f);
      }
    };

    load_tile(0);
    for (int kt=0; kt<nt; ++kt){
      __syncthreads();
      #pragma unroll
      for (int u=0;u<2;++u){
        const int li = tid + u*256;
        const int ar = li >> 3;
        const int kc = (li & 7) << 2;
        As[kc+0][ar] = pa[u].x; As[kc+1][ar] = pa[u].y;
        As[kc+2][ar] = pa[u].z; As[kc+3][ar] = pa[u].w;
      }
      #pragma unroll
      for (int u=0;u<4;++u){
        const int li = tid + u*256;
        const int br = li >> 3;
        const int kc = (li & 7) << 2;
        Bs[kc+0][br] = pb[u].x; Bs[kc+1][br] = pb[u].y;
        Bs[kc+2][br] = pb[u].z; Bs[kc+3][br] = pb[u].w;
      }
      __syncthreads();
      if (kt+1 < nt) load_tile(kt+1);
      #pragma unroll
      for (int kk=0;kk<BK;++kk){
        const float4 a0 = *(const float4*)&As[kk][ty<<2];
        const float4 b0 = *(const float4*)&Bs[kk][tx<<3];
        const float4 b1 = *(const float4*)&Bs[kk][(tx<<3)+4];
        const float av[4] = {a0.x,a0.y,a0.z,a0.w};
        const float bv[8] = {b0.x,b0.y,b0.z,b0.w,b1.x,b1.y,b1.z,b1.w};
        #pragma unroll
        for (int i=0;i<4;++i)
          #pragma unroll
          for (int j=0;j<8;++j)
            acc[i][j] = fmaf(av[i], bv[j], acc[i][j]);
      }
    }

    #pragma unroll
    for (int i=0;i<4;++i){
      const int gm = m0 + (ty<<2) + i;
      float* orow = d.out + (size_t)gm * d.N;
      #pragma unroll
      for (int j=0;j<8;++j){
        const int gn = n0 + (tx<<3) + j;
        if (gn < d.N){
          float x = acc[i][j];
          x = sigmf(x);          // g: ep==2, no bias
          orow[gn] = x;
        }
      }
    }
  }
}

// ---------------- fused prep: weight split (z<4) + fp32 premix (z>=4) -------------
#define NPL (Cc*Cc)
__global__ __launch_bounds__(256) void prep_kernel(
    const float* __restrict__ s0, const float* __restrict__ s1,
    const float* __restrict__ s2, const float* __restrict__ s3,
    unsigned short* __restrict__ planes,
    const float* __restrict__ hs, const float* __restrict__ xmix,
    float* __restrict__ p0, float* __restrict__ p1, float* __restrict__ p2)
{
  const int z = blockIdx.z;
  if (z < 4){
    if (blockIdx.x >= NPL/(256*4)) return;
    const float* src = z==0?s0:z==1?s1:z==2?s2:s3;
    unsigned short* dh = planes + (size_t)z*2*NPL;
    unsigned short* dl = dh + NPL;
    const size_t i = ((size_t)blockIdx.x*256 + threadIdx.x)*4;
    float4 v = ld4(src + i);
    unsigned hw0, lw0, hw1, lw1;
    split2(v.x, v.y, hw0, lw0);
    split2(v.z, v.w, hw1, lw1);
    uint2 hv; hv.x = hw0; hv.y = hw1;
    uint2 lv; lv.x = lw0; lv.y = lw1;
    *(uint2*)(dh + i) = hv;
    *(uint2*)(dl + i) = lv;
  } else {
    const int zz = z - 4;
    float* ph = zz==0?p0:(zz==1?p1:p2);
    const int mr = zz==0?0:(zz==1?2:3);
    const size_t o = ((size_t)blockIdx.x*256 + threadIdx.x)*4;
    const int gm = (int)(o >> 10);          // Cc = 1024
    const int kk = (int)(o & 1023);
    float4 h0 = ld4(hs + o);
    float4 mx = ld4(xmix + (size_t)mr*Cc + kk);
    float4 hp = make_float4(0.f,0.f,0.f,0.f);
    if ((gm & (Tt-1)) != 0) hp = ld4(hs + o - Cc);
    float4 r;
    r.x = h0.x + (hp.x - h0.x)*mx.x;
    r.y = h0.y + (hp.y - h0.y)*mx.y;
    r.z = h0.z + (hp.z - h0.z)*mx.z;
    r.w = h0.w + (hp.w - h0.w)*mx.w;
    *(float4*)(ph + o) = r;
  }
}

// ---------------- split-bf16 MFMA GEMM (big projections) ----------------
// v5 = v4 (DMA-B, swizzled source) + XCD-aware tile remap: linear in-slice id
// tile = x + 8y dispatches round-robin over the 8 XCDs; mapping m0=(tile&15),
// n0=(tile>>4) gives each XCD 2 A-rows (1 MB, L2-resident) + the whole W plane
// pair (4 MB, L2-resident) instead of streaming ALL of A per XCD (8x refetch).
#define TM 128
#define TN 128
#define LDBS 40   // bf16 row stride in LDS (A planes)

__global__ __launch_bounds__(256) void gemm_mfma(
    GemmDesc d0, GemmDesc d1, GemmDesc d2,
    const unsigned short* __restrict__ WH0, const unsigned short* __restrict__ WL0,
    const unsigned short* __restrict__ WH1, const unsigned short* __restrict__ WL1,
    const unsigned short* __restrict__ WH2, const unsigned short* __restrict__ WL2)
{
  const int z = blockIdx.z;
  GemmDesc d = z==0?d0:(z==1?d1:d2);
  const unsigned short* WH = z==0?WH0:(z==1?WH1:WH2);
  const unsigned short* WL = z==0?WL0:(z==1?WL1:WL2);
  const int tile = blockIdx.x + (blockIdx.y << 3);   // in-slice linear dispatch id
  const int m0 = (tile & 15) * TM;
  const int n0 = (tile >> 4) * TN;
  const int K  = d.K;
  const int tid = threadIdx.x;

  __shared__ __align__(16) unsigned short Ah[TM*LDBS], Al[TM*LDBS];
  __shared__ __align__(16) unsigned short Bh[2][TN*32], Bl[2][TN*32];

  const int sr = tid >> 1;
  const int sk = (tid & 1) << 4;
  const int gmA = m0 + sr;
  const int wv = tid >> 6, lane = tid & 63;

  float4 pa[4];
  auto load_A = [&](int kt){
    const int kb = kt*32 + sk;
    #pragma unroll
    for (int u=0;u<4;++u)
      pa[u] = ld4(d.A + (size_t)gmA*K + kb + 4*u);
  };
  auto stage_B = [&](int kt, int buf){
    #pragma unroll
    for (int c=0;c<2;++c){
      const int rl  = (c<<4) + (lane>>2);          // row within wave slab, 0..31
      const int row = (wv<<5) + rl;
      const unsigned lk = (unsigned)(((lane&3) ^ ((rl>>1)&3)) << 4);  // logical kbyte
      const size_t gb = (((size_t)(n0 + row)*K + kt*32) << 1) + lk;   // byte offset
      char* db = (char*)(&Bh[buf][0]) + (wv<<11) + (c<<10);           // wave-uniform
      gl2lds16((const float*)((const char*)WH + gb), (float*)db);
      char* dl = (char*)(&Bl[buf][0]) + (wv<<11) + (c<<10);
      gl2lds16((const float*)((const char*)WL + gb), (float*)dl);
    }
  };

  const int wm = (wv >> 1) << 6, wn = (wv & 1) << 6;
  const int fr = lane & 15;
  const int fk = (lane >> 4) << 3;

  f32x4 acc[4][4];
  const f32x4 z4 = {0.f,0.f,0.f,0.f};
  #pragma unroll
  for (int i=0;i<4;++i)
    #pragma unroll
    for (int j=0;j<4;++j) acc[i][j]=z4;

  const int nslab = K >> 5;
  load_A(0);
  stage_B(0, 0);
  for (int kt=0; kt<nslab; ++kt){
    __syncthreads();                       // prior MFMA reads of Ah/Al done
    {
      unsigned hw[8], lw[8];
      #pragma unroll
      for (int u=0;u<4;++u){
        const float xs[4] = {pa[u].x, pa[u].y, pa[u].z, pa[u].w};
        split2(xs[0], xs[1], hw[u*2+0], lw[u*2+0]);
        split2(xs[2], xs[3], hw[u*2+1], lw[u*2+1]);
      }
      uint4 t;
      t.x=hw[0];t.y=hw[1];t.z=hw[2];t.w=hw[3]; *(uint4*)&Ah[sr*LDBS+sk]   = t;
      t.x=hw[4];t.y=hw[5];t.z=hw[6];t.w=hw[7]; *(uint4*)&Ah[sr*LDBS+sk+8] = t;
      t.x=lw[0];t.y=lw[1];t.z=lw[2];t.w=lw[3]; *(uint4*)&Al[sr*LDBS+sk]   = t;
      t.x=lw[4];t.y=lw[5];t.z=lw[6];t.w=lw[7]; *(uint4*)&Al[sr*LDBS+sk+8] = t;
    }
    __builtin_amdgcn_s_waitcnt(0x0F70);    // vmcnt(0): this tile's B-DMA landed
    __syncthreads();
    if (kt+1 < nslab){ load_A(kt+1); stage_B(kt+1, (kt+1)&1); }

    const unsigned short* BhT = &Bh[kt&1][0];
    const unsigned short* BlT = &Bl[kt&1][0];
    short8 bh4[4], bl4[4];
    #pragma unroll
    for (int nt=0;nt<4;++nt){
      const int rowB = wn + nt*16 + fr;
      const int so = rowB*32 + (fk ^ (((rowB>>1)&3)<<3));   // swizzled read
      bh4[nt] = *(const short8*)&BhT[so];
      bl4[nt] = *(const short8*)&BlT[so];
    }
    #pragma unroll
    for (int mt=0;mt<4;++mt){
      const short8 ah = *(const short8*)&Ah[(wm + mt*16 + fr)*LDBS + fk];
      const short8 al = *(const short8*)&Al[(wm + mt*16 + fr)*LDBS + fk];
      #pragma unroll
      for (int nt=0;nt<4;++nt)
        acc[mt][nt] = __builtin_amdgcn_mfma_f32_16x16x32_bf16(ah, bh4[nt], acc[mt][nt], 0,0,0);
      #pragma unroll
      for (int nt=0;nt<4;++nt)
        acc[mt][nt] = __builtin_amdgcn_mfma_f32_16x16x32_bf16(ah, bl4[nt], acc[mt][nt], 0,0,0);
      #pragma unroll
      for (int nt=0;nt<4;++nt)
        acc[mt][nt] = __builtin_amdgcn_mfma_f32_16x16x32_bf16(al, bh4[nt], acc[mt][nt], 0,0,0);
    }
  }

  #pragma unroll
  for (int mt=0;mt<4;++mt){
    #pragma unroll
    for (int nt=0;nt<4;++nt){
      #pragma unroll
      for (int r=0;r<4;++r){
        const int row = wm + mt*16 + ((lane>>4)<<2) + r;
        const int col = wn + nt*16 + fr;
        d.out[(size_t)(m0+row)*d.N + n0 + col] = acc[mt][nt][r];
      }
    }
  }
}

// ---------------- per-head prep (in-place coefficient precompute) ----------------
__global__ __launch_bounds__(256) void head_prep(
    float* kbuf, float* awbuf, float* svwbuf, float* wbbuf, float* vbuf,
    const float* __restrict__ vfirst,
    const float* __restrict__ k_k, const float* __restrict__ k_a)
{
  const int gid = blockIdx.x*4 + (threadIdx.x>>6);
  const int e = threadIdx.x & 63;
  const int m = gid >> 4;
  const int h = gid & 15;
  const int c = h*Dd + e;
  const size_t idx = (size_t)m*Cc + c;
  const float kv0 = kbuf[idx];
  const float av  = awbuf[idx];
  const float sv  = svwbuf[idx];
  const float wv  = wbbuf[idx];
  const float v0  = vbuf[idx];
  const float vf  = vfirst[idx];
  const float kku = kv0 * k_k[c];
  const float ss  = wredsum(kku*kku);
  const float kkn = kku / fmaxf(sqrtf(ss), 1e-12f);
  const float ew  = expf(wv);
  kbuf[idx]  = kv0 * (1.f + (av - 1.f)*k_a[c]);
  awbuf[idx] = ew;
  svwbuf[idx]= -kkn * ew;
  wbbuf[idx] = kkn * av;
  vbuf[idx]  = v0 + sv*(vf - v0);
}

// ---------------- sequential scan v13: 4-deep register pipeline + counted vmcnt ----
#define NB (Tt/16)
struct Coef { float4 Lw, Ew, Bq, Kq, Rq; float Vv; };
__global__ __launch_bounds__(64) void scan_kernel(
    const float* __restrict__ lawb, const float* __restrict__ ewb,
    const float* __restrict__ bbb,  const float* __restrict__ kb,
    const float* __restrict__ rb,   const float* __restrict__ vb,
    float* __restrict__ outp)
{
  const int blk  = blockIdx.x;
  const int bh   = blk & 31;        // chain id; 16 blocks %32-congruent -> same XCD
  const int blkc = blk >> 5;        // 0..15: column quad
  const int b = bh >> 4, h = bh & 15;
  const int lane = threadIdx.x;
  const int es = lane >> 4;         // column slot 0..3
  const int rd = lane & 15;         // row quad (rows 4rd..4rd+3)
  const int colb = blkc * 4;
  const int hb = h * Dd;
  const int la = 4*rd;              // dword offset of this lane's row quad

  // per buffer: law[1024] ew[1024] bb[1024] k[1024] r[1024] v[64]
  __shared__ __align__(16) float LB[2][5*1024 + 64];

  float S0=0.f, S1=0.f, S2=0.f, S3=0.f;
  float4 Rp = make_float4(0.f,0.f,0.f,0.f);   // r of previous step (r_{g-1})
  const size_t mbase = (size_t)b*Tt;
  float* ocol = outp + mbase*Cc + hb + colb + es;   // column base for rd==0 stores

  const int qrow = lane >> 4;           // staging: row within 4-row slab
  const int qcol = (lane & 15) * 4;     // staging: dword col

  auto stage = [&](int bt){
    const size_t g0 = (mbase + (size_t)bt*16)*Cc + hb;
    float* dst = &LB[bt&1][0];
    const float* srcs[5] = {lawb, ewb, bbb, kb, rb};
    #pragma unroll
    for (int a=0;a<5;++a){
      const float* s = srcs[a] + g0 + (size_t)qrow*Cc + qcol;
      #pragma unroll
      for (int i=0;i<4;++i)
        gl2lds16(s + (size_t)(4*i)*Cc, dst + a*1024 + i*256);
    }
    gl2lds4(vb + g0 + (size_t)(lane>>2)*Cc + colb + (lane&3), dst + 5120);
  };

  stage(0);
  __builtin_amdgcn_s_waitcnt(0x0F70);   // vmcnt(0): batch 0's DMA complete

  for (int bt = 0; bt < NB; ++bt){
    if (bt+1 < NB) stage(bt+1);           // in flight under this batch's compute
    const float* cb2 = &LB[bt&1][0];

    auto ldq = [&](int t, Coef& c){
      c.Lw = *(const float4*)&cb2[         t*64 + la];
      c.Ew = *(const float4*)&cb2[1024 + t*64 + la];
      c.Bq = *(const float4*)&cb2[2048 + t*64 + la];
      c.Kq = *(const float4*)&cb2[3072 + t*64 + la];
      c.Rq = *(const float4*)&cb2[4096 + t*64 + la];
      c.Vv = cb2[5120 + t*4 + es];
    };

    Coef cA, cB, cC, cD;
    ldq(0, cA); ldq(1, cB); ldq(2, cC); ldq(3, cD);

    auto stepf = [&](int t, Coef& c){
      const float4 Lw = c.Lw, Ew = c.Ew, Bq = c.Bq, Kq = c.Kq, rr = c.Rq;
      const float vv = c.Vv;
      // both dots read S_old: ta for THIS step's update, op for PREVIOUS step's output
      float tp = fmaf(Lw.y, S1, Lw.x*S0);
      float tb = fmaf(Lw.w, S3, Lw.z*S2);
      tp += tb;
      float op = fmaf(Rp.y, S1, Rp.x*S0);
      float ob = fmaf(Rp.w, S3, Rp.z*S2);
      op += ob;
      dsum16x2(tp, op);                       // interleaved: op hides under tp's chain
      // store out(g-1); only batch 0 / t==0 has no predecessor
      const bool gv = (bt > 0) | (t > 0);
      if (gv && rd == 0)
        ocol[(size_t)(bt*16 + t - 1)*Cc] = op;
      S0 = fmaf(Ew.x, S0, fmaf(Bq.x, tp, Kq.x*vv));
      S1 = fmaf(Ew.y, S1, fmaf(Bq.y, tp, Kq.y*vv));
      S2 = fmaf(Ew.z, S2, fmaf(Bq.z, tp, Kq.z*vv));
      S3 = fmaf(Ew.w, S3, fmaf(Bq.w, tp, Kq.w*vv));
      Rp = rr;                                // r_g becomes r_{g-1} for next step
      if (t+4 < 16) ldq(t+4, c);              // refill same buffer, 4 steps ahead
    };

    #pragma unroll
    for (int t = 0; t < 16; ++t){
      const int s = t & 3;
      if      (s == 0) stepf(t, cA);
      else if (s == 1) stepf(t, cB);
      else if (s == 2) stepf(t, cC);
      else             stepf(t, cD);
    }

    // counted wait: stage(bt+1)'s 22 DMA ops are the OLDEST outstanding vm ops;
    // <=16 output stores were issued after them. vmcnt(16) => all DMA landed.
    if (bt+1 < NB) __builtin_amdgcn_s_waitcnt(0x4F70);   // vmcnt(16)
  }

  // flush: out(T-1) = r_{T-1} . S(T-1)
  {
    float op = fmaf(Rp.y, S1, Rp.x*S0);
    float ob = fmaf(Rp.w, S3, Rp.z*S2);
    op = dsum16(op + ob);
    if (rd == 0)
      ocol[(size_t)(Tt - 1)*Cc] = op;
  }
}

// ---------------- GroupNorm + correction + g gating ----------------
__global__ __launch_bounds__(256) void epilogue_kernel(
    const float* __restrict__ att, const float* __restrict__ rbuf,
    const float* __restrict__ kbuf, const float* __restrict__ vbuf,
    const float* __restrict__ gbuf,
    const float* __restrict__ r_k, const float* __restrict__ gn_w,
    const float* __restrict__ gn_b, float* __restrict__ opre)
{
  const int gid = blockIdx.x*4 + (threadIdx.x>>6);
  const int e = threadIdx.x & 63;
  const int m = gid >> 4;
  const int h = gid & 15;
  const int c = h*Dd + e;
  const size_t idx = (size_t)m*Cc + c;
  const float x  = att[idx];
  const float mu = wredsum(x) * (1.f/Dd);
  const float xd = x - mu;
  const float var = wredsum(xd*xd) * (1.f/Dd);
  const float og = xd * (1.f/sqrtf(var + GN_EPS)) * gn_w[c] + gn_b[c];
  const float rv = rbuf[idx], kv = kbuf[idx], vv = vbuf[idx];
  const float cd = wredsum(rv*kv*r_k[c]);
  opre[idx] = (og + cd*vv) * gbuf[idx];
}

extern "C" void kernel_launch(void* const* d_in, const int* in_sizes, int n_in,
                              void* d_out, int out_size, void* d_ws, size_t ws_size,
                              hipStream_t stream)
{
  (void)in_sizes; (void)n_in; (void)out_size; (void)ws_size;
  const float* hs     = (const float*)d_in[0];
  const float* vfirst = (const float*)d_in[1];
  const float* xmix   = (const float*)d_in[2];
  const float* k_k    = (const float*)d_in[3];
  const float* k_a    = (const float*)d_in[4];
  const float* r_k    = (const float*)d_in[5];
  const float* W_r    = (const float*)d_in[6];
  const float* W_k    = (const float*)d_in[7];
  const float* W_v    = (const float*)d_in[8];
  const float* W_o    = (const float*)d_in[9];
  const float* w_A    = (const float*)d_in[10];
  const float* w_B    = (const float*)d_in[11];
  const float* w_b    = (const float*)d_in[12];
  const float* a_A    = (const float*)d_in[13];
  const float* a_B    = (const float*)d_in[14];
  const float* a_b    = (const float*)d_in[15];
  const float* v_A    = (const float*)d_in[16];
  const float* v_B    = (const float*)d_in[17];
  const float* v_b    = (const float*)d_in[18];
  const float* g_A    = (const float*)d_in[19];
  const float* g_B    = (const float*)d_in[20];
  const float* gn_w   = (const float*)d_in[21];
  const float* gn_b   = (const float*)d_in[22];
  float* out = (float*)d_out;
  float* ws  = (float*)d_ws;

  const size_t MC = (size_t)Mm * Cc;
  float* Br   = ws;            // r
  float* Bw   = ws + MC;       // [premix xr] -> w/bb (L3/L4) -> o_pre (epilogue)
  float* Bk   = ws + 2*MC;     // k0 -> kfin
  float* Bkk  = ws + 3*MC;     // [premix xk] -> sv -> law
  float* Bv   = ws + 4*MC;     // v0 -> v
  float* Ba   = ws + 5*MC;     // [premix xv] -> a -> ew
  float* Batt = ws + 6*MC;     // scan output
  float* Bg   = ws + 7*MC;     // g
  float* T1w  = ws + 8*MC;
  float* T1a  = T1w + (size_t)Mm*64;
  float* T1v  = T1a + (size_t)Mm*64;
  float* T1g  = T1v + (size_t)Mm*64;   // Mm*160 floats
  unsigned short* WP = (unsigned short*)(ws + 8*MC + (size_t)Mm*352);
  unsigned short* WrH = WP + 0*(size_t)NPL, *WrL = WP + 1*(size_t)NPL;
  unsigned short* WkH = WP + 2*(size_t)NPL, *WkL = WP + 3*(size_t)NPL;
  unsigned short* WvH = WP + 4*(size_t)NPL, *WvL = WP + 5*(size_t)NPL;
  unsigned short* WoH = WP + 6*(size_t)NPL, *WoL = WP + 7*(size_t)NPL;

  dim3 blk(256,1,1);

  // L0: fused weight split + fp32 premix (xr -> Bw, xk -> Bkk, xv -> Ba)
  prep_kernel<<<dim3(Mm*Cc/(256*4),1,7), blk, 0, stream>>>(
      W_r, W_k, W_v, W_o, WP, hs, xmix, Bw, Bkk, Ba);

  // L1: big projections r, k0, v0 via split-bf16 MFMA (premixed fp32 A, DMA B,
  // XCD-aware tile remap)
  GemmDesc dr{Bw,  W_r, Br, nullptr, Cc, Cc, -1, 0};
  GemmDesc dk{Bkk, W_k, Bk, nullptr, Cc, Cc, -1, 0};
  GemmDesc dv{Ba,  W_v, Bv, nullptr, Cc, Cc, -1, 0};
  gemm_mfma<<<dim3(Cc/TN, Mm/TM, 3), blk, 0, stream>>>(
      dr, dk, dv, WrH, WrL, WkH, WkL, WvH, WvL);

  // L2: LoRA stage-1 (w/a/v on 64-wide path, g on 128-wide path)
  GemmDesc s1w{nullptr, w_A, T1w, nullptr, 64, Cc, 1, 1};
  GemmDesc s1a{nullptr, a_A, T1a, nullptr, 64, Cc, 4, 0};
  GemmDesc s1v{nullptr, v_A, T1v, nullptr, 64, Cc, 3, 0};
  GemmDesc s1g{nullptr, g_A, T1g, nullptr, 160, Cc, 5, 2};
  lora1_kernel<<<dim3(2,32,4), blk, 0, stream>>>(s1w,s1a,s1v,s1g, xmix, hs);

  // L3: LoRA stage-2 (overwrites the premix buffers — dead by now)
  GemmDesc s2w{T1w, w_B, Bw,  w_b,    Cc, 64,  -1, 3};
  GemmDesc s2a{T1a, a_B, Ba,  a_b,    Cc, 64,  -1, 2};
  GemmDesc s2v{T1v, v_B, Bkk, v_b,    Cc, 64,  -1, 2};
  GemmDesc s2g{T1g, g_B, Bg,  nullptr,Cc, 160, -1, 0};
  gemm_kernel<<<dim3(8,32,4), blk, 0, stream>>>(s2w,s2a,s2v,s2g, xmix, hs);

  // L4: per-head prep; in place: Bk k0->kfin, Ba a->ew, Bkk sv->law, Bw w->bb, Bv v0->v
  head_prep<<<dim3(Mm*Hh/4), blk, 0, stream>>>(Bk, Ba, Bkk, Bw, Bv,
                                               vfirst, k_k, k_a);

  // L5: sequential scan (v13: 4-deep reg pipeline, counted vmcnt, no barriers)
  scan_kernel<<<dim3(512), dim3(64), 0, stream>>>(Bkk, Ba, Bw, Bk, Br, Bv, Batt);

  // L6: groupnorm + corr + g -> o_pre (reuse Bw; bb dead after scan)
  epilogue_kernel<<<dim3(Mm*Hh/4), blk, 0, stream>>>(Batt, Br, Bk, Bv, Bg,
                                                     r_k, gn_w, gn_b, Bw);

  // L7: output projection via split-bf16 MFMA
  GemmDesc doo{Bw, W_o, out, nullptr, Cc, Cc, -1, 0};
  gemm_mfma<<<dim3(Cc/TN, Mm/TM, 1), blk, 0, stream>>>(
      doo, doo, doo, WoH, WoL, WoH, WoL, WoH, WoL);
}

// Round 16
// 484.586 us; speedup vs baseline: 1.3257x; 1.0684x over previous
//
#include <hip/hip_runtime.h>
#include <math.h>

#define Bb 2
#define Tt 1024
#define HALF 512
#define Cc 1024
#define Hh 16
#define Dd 64
#define Mm (Bb*Tt)
#define DECAY_SCALE (-0.6065306597126334f)
#define GN_EPS (64e-5f)

typedef __attribute__((ext_vector_type(8))) short short8;   // 8 bf16 (4 VGPRs)
typedef __attribute__((ext_vector_type(4))) float f32x4;    // MFMA acc

struct GemmDesc {
  const float* A;      // used when mixrow < 0 (row stride = K)
  const float* W;      // (N, K) row-major
  float* out;          // (M, N) row-major
  const float* bias;   // per-n bias or nullptr
  int N, K;
  int mixrow;          // >=0: A = token-shift mix of hidden_states with x_mix[mixrow]
  int ep;              // 0 none, 1 tanh, 2 sigmoid(x+bias?), 3 DECAY*sigmoid(x+bias)
};

__device__ __forceinline__ float4 ld4(const float* p){ return *reinterpret_cast<const float4*>(p); }
__device__ __forceinline__ float sigmf(float x){ return 1.f/(1.f+expf(-x)); }

__device__ __forceinline__ float wredsum(float x){
  #pragma unroll
  for (int off=32; off>0; off>>=1) x += __shfl_xor(x, off);
  return x;
}

template<int CTRL>
__device__ __forceinline__ float dppadd(float x){
  return x + __int_as_float(__builtin_amdgcn_update_dpp(0, __float_as_int(x), CTRL, 0xF, 0xF, true));
}

// 16-lane sum (lanes 16k..16k+15), pure DPP (VALU speed, no LDS pipe).
__device__ __forceinline__ float dsum16(float x){
  x = dppadd<0xB1>(x);
  x = dppadd<0x4E>(x);
  x = dppadd<0x141>(x);
  x = dppadd<0x140>(x);
  return x;
}

// two independent 16-lane sums, explicitly interleaved so the second chain's
// DPP latency hides under the first chain's stalls (single-wave in-order issue).
__device__ __forceinline__ void dsum16x2(float& x, float& y){
  x = dppadd<0xB1>(x);  y = dppadd<0xB1>(y);
  x = dppadd<0x4E>(x);  y = dppadd<0x4E>(y);
  x = dppadd<0x141>(x); y = dppadd<0x141>(y);
  x = dppadd<0x140>(x); y = dppadd<0x140>(y);
}

// async global -> LDS DMA (16 B / 4 B per lane); dest = wave-uniform base + lane*size
__device__ __forceinline__ void gl2lds16(const float* g, float* l){
  __builtin_amdgcn_global_load_lds(
      (const __attribute__((address_space(1))) unsigned int*)g,
      (__attribute__((address_space(3))) unsigned int*)l, 16, 0, 0);
}
__device__ __forceinline__ void gl2lds4(const float* g, float* l){
  __builtin_amdgcn_global_load_lds(
      (const __attribute__((address_space(1))) unsigned int*)g,
      (__attribute__((address_space(3))) unsigned int*)l, 4, 0, 0);
}

// split one fp32 value pair into packed bf16 hi/lo words
__device__ __forceinline__ void split2(const float a, const float b,
                                       unsigned& hw, unsigned& lw){
  unsigned u0 = __float_as_uint(a);
  unsigned u1 = __float_as_uint(b);
  float l0 = a - __uint_as_float(u0 & 0xFFFF0000u);
  float l1 = b - __uint_as_float(u1 & 0xFFFF0000u);
  hw = (u0>>16) | (u1 & 0xFFFF0000u);
  lw = (__float_as_uint(l0)>>16) | (__float_as_uint(l1) & 0xFFFF0000u);
}

#define BM 64
#define BN 128
#define BK 32

// ---------------- vector-ALU GEMM (LoRA stage-2) ----------------
__global__ __launch_bounds__(256) void gemm_kernel(
    GemmDesc d0, GemmDesc d1, GemmDesc d2, GemmDesc d3,
    const float* __restrict__ xmix, const float* __restrict__ hs)
{
  GemmDesc d = (blockIdx.z==0)?d0:(blockIdx.z==1)?d1:(blockIdx.z==2)?d2:d3;
  const int n0 = blockIdx.x * BN;
  if (n0 >= d.N) return;            // block-uniform
  const int m0 = blockIdx.y * BM;
  const int tid = threadIdx.x;
  __shared__ float As[BK][BM+4];
  __shared__ float Bs[BK][BN+4];
  const int ty = tid >> 4, tx = tid & 15;

  float acc[4][8];
  #pragma unroll
  for (int i=0;i<4;++i)
    #pragma unroll
    for (int j=0;j<8;++j) acc[i][j]=0.f;

  const int K = d.K;
  const int nt = K / BK;
  const float* mrow = (d.mixrow >= 0) ? (xmix + (size_t)d.mixrow * Cc) : nullptr;
  float4 pa[2], pb[4];

  auto load_tile = [&](int kt){
    const int kbase = kt * BK;
    #pragma unroll
    for (int u=0;u<2;++u){
      const int li = tid + u*256;
      const int ar = li >> 3;
      const int kk = ((li & 7) << 2) + kbase;
      const int gm = m0 + ar;
      if (mrow){
        float4 h0 = ld4(hs + (size_t)gm*Cc + kk);
        float4 mx = ld4(mrow + kk);
        float4 hp = make_float4(0.f,0.f,0.f,0.f);
        if ((gm & (Tt-1)) != 0) hp = ld4(hs + (size_t)(gm-1)*Cc + kk);
        pa[u].x = h0.x + (hp.x - h0.x)*mx.x;
        pa[u].y = h0.y + (hp.y - h0.y)*mx.y;
        pa[u].z = h0.z + (hp.z - h0.z)*mx.z;
        pa[u].w = h0.w + (hp.w - h0.w)*mx.w;
      } else {
        pa[u] = ld4(d.A + (size_t)gm*K + kk);
      }
    }
    #pragma unroll
    for (int u=0;u<4;++u){
      const int li = tid + u*256;
      const int br = li >> 3;
      const int kk = ((li & 7) << 2) + kbase;
      const int gn = n0 + br;
      pb[u] = (gn < d.N) ? ld4(d.W + (size_t)gn*K + kk) : make_float4(0.f,0.f,0.f,0.f);
    }
  };

  load_tile(0);
  for (int kt=0; kt<nt; ++kt){
    __syncthreads();
    #pragma unroll
    for (int u=0;u<2;++u){
      const int li = tid + u*256;
      const int ar = li >> 3;
      const int kc = (li & 7) << 2;
      As[kc+0][ar] = pa[u].x; As[kc+1][ar] = pa[u].y;
      As[kc+2][ar] = pa[u].z; As[kc+3][ar] = pa[u].w;
    }
    #pragma unroll
    for (int u=0;u<4;++u){
      const int li = tid + u*256;
      const int br = li >> 3;
      const int kc = (li & 7) << 2;
      Bs[kc+0][br] = pb[u].x; Bs[kc+1][br] = pb[u].y;
      Bs[kc+2][br] = pb[u].z; Bs[kc+3][br] = pb[u].w;
    }
    __syncthreads();
    if (kt+1 < nt) load_tile(kt+1);
    #pragma unroll
    for (int kk=0;kk<BK;++kk){
      const float4 a0 = *(const float4*)&As[kk][ty<<2];
      const float4 b0 = *(const float4*)&Bs[kk][tx<<3];
      const float4 b1 = *(const float4*)&Bs[kk][(tx<<3)+4];
      const float av[4] = {a0.x,a0.y,a0.z,a0.w};
      const float bv[8] = {b0.x,b0.y,b0.z,b0.w,b1.x,b1.y,b1.z,b1.w};
      #pragma unroll
      for (int i=0;i<4;++i)
        #pragma unroll
        for (int j=0;j<8;++j)
          acc[i][j] = fmaf(av[i], bv[j], acc[i][j]);
    }
  }

  const int ep = d.ep;
  #pragma unroll
  for (int i=0;i<4;++i){
    const int gm = m0 + (ty<<2) + i;
    float* orow = d.out + (size_t)gm * d.N;
    #pragma unroll
    for (int j=0;j<8;++j){
      const int gn = n0 + (tx<<3) + j;
      if (gn < d.N){
        float x = acc[i][j];
        if (ep==1) x = tanhf(x);
        else if (ep==2){ if (d.bias) x += d.bias[gn]; x = sigmf(x); }
        else if (ep==3){ x += d.bias[gn]; x = DECAY_SCALE * sigmf(x); }
        orow[gn] = x;
      }
    }
  }
}

// ---------------- LoRA stage-1: N=64 slices on a BN=64 tile (z<3) + g (z==3) ------
__global__ __launch_bounds__(256) void lora1_kernel(
    GemmDesc e0, GemmDesc e1, GemmDesc e2, GemmDesc e3,
    const float* __restrict__ xmix, const float* __restrict__ hs)
{
  __shared__ __align__(16) unsigned char SMEM[25600];
  const int z = blockIdx.z;
  const int tid = threadIdx.x;

  if (z < 3){
    if (blockIdx.x != 0) return;
    GemmDesc d = (z==0)?e0:(z==1)?e1:e2;
    const int m0 = blockIdx.y * BM;
    float (*As)[BM+4] = reinterpret_cast<float(*)[BM+4]>(SMEM);
    float (*Bs)[BM+4] = reinterpret_cast<float(*)[BM+4]>(SMEM + sizeof(float)*BK*(BM+4));
    const int ty = tid >> 4, tx = tid & 15;

    float acc[4][4];
    #pragma unroll
    for (int i=0;i<4;++i)
      #pragma unroll
      for (int j=0;j<4;++j) acc[i][j]=0.f;

    const int K = d.K;
    const int nt = K / BK;
    const float* mrow = xmix + (size_t)d.mixrow * Cc;
    float4 pa[2], pb[2];

    auto load_tile = [&](int kt){
      const int kbase = kt * BK;
      #pragma unroll
      for (int u=0;u<2;++u){
        const int li = tid + u*256;
        const int ar = li >> 3;
        const int kk = ((li & 7) << 2) + kbase;
        const int gm = m0 + ar;
        float4 h0 = ld4(hs + (size_t)gm*Cc + kk);
        float4 mx = ld4(mrow + kk);
        float4 hp = make_float4(0.f,0.f,0.f,0.f);
        if ((gm & (Tt-1)) != 0) hp = ld4(hs + (size_t)(gm-1)*Cc + kk);
        pa[u].x = h0.x + (hp.x - h0.x)*mx.x;
        pa[u].y = h0.y + (hp.y - h0.y)*mx.y;
        pa[u].z = h0.z + (hp.z - h0.z)*mx.z;
        pa[u].w = h0.w + (hp.w - h0.w)*mx.w;
        pb[u] = ld4(d.W + (size_t)ar*K + kk);
      }
    };

    load_tile(0);
    for (int kt=0; kt<nt; ++kt){
      __syncthreads();
      #pragma unroll
      for (int u=0;u<2;++u){
        const int li = tid + u*256;
        const int ar = li >> 3;
        const int kc = (li & 7) << 2;
        As[kc+0][ar] = pa[u].x; As[kc+1][ar] = pa[u].y;
        As[kc+2][ar] = pa[u].z; As[kc+3][ar] = pa[u].w;
        Bs[kc+0][ar] = pb[u].x; Bs[kc+1][ar] = pb[u].y;
        Bs[kc+2][ar] = pb[u].z; Bs[kc+3][ar] = pb[u].w;
      }
      __syncthreads();
      if (kt+1 < nt) load_tile(kt+1);
      #pragma unroll
      for (int kk=0;kk<BK;++kk){
        const float4 a0 = *(const float4*)&As[kk][ty<<2];
        const float4 b0 = *(const float4*)&Bs[kk][tx<<2];
        const float av[4] = {a0.x,a0.y,a0.z,a0.w};
        const float bv[4] = {b0.x,b0.y,b0.z,b0.w};
        #pragma unroll
        for (int i=0;i<4;++i)
          #pragma unroll
          for (int j=0;j<4;++j)
            acc[i][j] = fmaf(av[i], bv[j], acc[i][j]);
      }
    }

    const int ep = d.ep;
    #pragma unroll
    for (int i=0;i<4;++i){
      const int gm = m0 + (ty<<2) + i;
      float* orow = d.out + (size_t)gm * d.N;
      #pragma unroll
      for (int j=0;j<4;++j){
        const int gn = (tx<<2) + j;
        float x = acc[i][j];
        if (ep==1) x = tanhf(x);
        orow[gn] = x;
      }
    }
  } else {
    GemmDesc d = e3;
    const int n0 = blockIdx.x * BN;
    if (n0 >= d.N) return;
    const int m0 = blockIdx.y * BM;
    float (*As)[BM+4] = reinterpret_cast<float(*)[BM+4]>(SMEM);
    float (*Bs)[BN+4] = reinterpret_cast<float(*)[BN+4]>(SMEM + sizeof(float)*BK*(BM+4));
    const int ty = tid >> 4, tx = tid & 15;

    float acc[4][8];
    #pragma unroll
    for (int i=0;i<4;++i)
      #pragma unroll
      for (int j=0;j<8;++j) acc[i][j]=0.f;

    const int K = d.K;
    const int nt = K / BK;
    const float* mrow = xmix + (size_t)d.mixrow * Cc;
    float4 pa[2], pb[4];

    auto load_tile = [&](int kt){
      const int kbase = kt * BK;
      #pragma unroll
      for (int u=0;u<2;++u){
        const int li = tid + u*256;
        const int ar = li >> 3;
        const int kk = ((li & 7) << 2) + kbase;
        const int gm = m0 + ar;
        float4 h0 = ld4(hs + (size_t)gm*Cc + kk);
        float4 mx = ld4(mrow + kk);
        float4 hp = make_float4(0.f,0.f,0.f,0.f);
        if ((gm & (Tt-1)) != 0) hp = ld4(hs + (size_t)(gm-1)*Cc + kk);
        pa[u].x = h0.x + (hp.x - h0.x)*mx.x;
        pa[u].y = h0.y + (hp.y - h0.y)*mx.y;
        pa[u].z = h0.z + (hp.z - h0.z)*mx.z;
        pa[u].w = h0.w + (hp.w - h0.w)*mx.w;
      }
      #pragma unroll
      for (int u=0;u<4;++u){
        const int li = tid + u*256;
        const int br = li >> 3;
        const int kk = ((li & 7) << 2) + kbase;
        const int gn = n0 + br;
        pb[u] = (gn < d.N) ? ld4(d.W + (size_t)gn*K + kk) : make_float4(0.f,0.f,0.f,0.f);
      }
    };

    load_tile(0);
    for (int kt=0; kt<nt; ++kt){
      __syncthreads();
      #pragma unroll
      for (int u=0;u<2;++u){
        const int li = tid + u*256;
        const int ar = li >> 3;
        const int kc = (li & 7) << 2;
        As[kc+0][ar] = pa[u].x; As[kc+1][ar] = pa[u].y;
        As[kc+2][ar] = pa[u].z; As[kc+3][ar] = pa[u].w;
      }
      #pragma unroll
      for (int u=0;u<4;++u){
        const int li = tid + u*256;
        const int br = li >> 3;
        const int kc = (li & 7) << 2;
        Bs[kc+0][br] = pb[u].x; Bs[kc+1][br] = pb[u].y;
        Bs[kc+2][br] = pb[u].z; Bs[kc+3][br] = pb[u].w;
      }
      __syncthreads();
      if (kt+1 < nt) load_tile(kt+1);
      #pragma unroll
      for (int kk=0;kk<BK;++kk){
        const float4 a0 = *(const float4*)&As[kk][ty<<2];
        const float4 b0 = *(const float4*)&Bs[kk][tx<<3];
        const float4 b1 = *(const float4*)&Bs[kk][(tx<<3)+4];
        const float av[4] = {a0.x,a0.y,a0.z,a0.w};
        const float bv[8] = {b0.x,b0.y,b0.z,b0.w,b1.x,b1.y,b1.z,b1.w};
        #pragma unroll
        for (int i=0;i<4;++i)
          #pragma unroll
          for (int j=0;j<8;++j)
            acc[i][j] = fmaf(av[i], bv[j], acc[i][j]);
      }
    }

    #pragma unroll
    for (int i=0;i<4;++i){
      const int gm = m0 + (ty<<2) + i;
      float* orow = d.out + (size_t)gm * d.N;
      #pragma unroll
      for (int j=0;j<8;++j){
        const int gn = n0 + (tx<<3) + j;
        if (gn < d.N){
          float x = acc[i][j];
          x = sigmf(x);
          orow[gn] = x;
        }
      }
    }
  }
}

// ---------------- fused prep: weight split (z<4) + fp32 premix (z>=4) -------------
#define NPL (Cc*Cc)
__global__ __launch_bounds__(256) void prep_kernel(
    const float* __restrict__ s0, const float* __restrict__ s1,
    const float* __restrict__ s2, const float* __restrict__ s3,
    unsigned short* __restrict__ planes,
    const float* __restrict__ hs, const float* __restrict__ xmix,
    float* __restrict__ p0, float* __restrict__ p1, float* __restrict__ p2)
{
  const int z = blockIdx.z;
  if (z < 4){
    if (blockIdx.x >= NPL/(256*4)) return;
    const float* src = z==0?s0:z==1?s1:z==2?s2:s3;
    unsigned short* dh = planes + (size_t)z*2*NPL;
    unsigned short* dl = dh + NPL;
    const size_t i = ((size_t)blockIdx.x*256 + threadIdx.x)*4;
    float4 v = ld4(src + i);
    unsigned hw0, lw0, hw1, lw1;
    split2(v.x, v.y, hw0, lw0);
    split2(v.z, v.w, hw1, lw1);
    uint2 hv; hv.x = hw0; hv.y = hw1;
    uint2 lv; lv.x = lw0; lv.y = lw1;
    *(uint2*)(dh + i) = hv;
    *(uint2*)(dl + i) = lv;
  } else {
    const int zz = z - 4;
    float* ph = zz==0?p0:(zz==1?p1:p2);
    const int mr = zz==0?0:(zz==1?2:3);
    const size_t o = ((size_t)blockIdx.x*256 + threadIdx.x)*4;
    const int gm = (int)(o >> 10);          // Cc = 1024
    const int kk = (int)(o & 1023);
    float4 h0 = ld4(hs + o);
    float4 mx = ld4(xmix + (size_t)mr*Cc + kk);
    float4 hp = make_float4(0.f,0.f,0.f,0.f);
    if ((gm & (Tt-1)) != 0) hp = ld4(hs + o - Cc);
    float4 r;
    r.x = h0.x + (hp.x - h0.x)*mx.x;
    r.y = h0.y + (hp.y - h0.y)*mx.y;
    r.z = h0.z + (hp.z - h0.z)*mx.z;
    r.w = h0.w + (hp.w - h0.w)*mx.w;
    *(float4*)(ph + o) = r;
  }
}

// ---------------- split-bf16 MFMA GEMM (big projections) ----------------
#define TM 128
#define TN 128
#define LDBS 40   // bf16 row stride in LDS (A planes)

__global__ __launch_bounds__(256) void gemm_mfma(
    GemmDesc d0, GemmDesc d1, GemmDesc d2,
    const unsigned short* __restrict__ WH0, const unsigned short* __restrict__ WL0,
    const unsigned short* __restrict__ WH1, const unsigned short* __restrict__ WL1,
    const unsigned short* __restrict__ WH2, const unsigned short* __restrict__ WL2)
{
  const int z = blockIdx.z;
  GemmDesc d = z==0?d0:(z==1?d1:d2);
  const unsigned short* WH = z==0?WH0:(z==1?WH1:WH2);
  const unsigned short* WL = z==0?WL0:(z==1?WL1:WL2);
  const int tile = blockIdx.x + (blockIdx.y << 3);   // in-slice linear dispatch id
  const int m0 = (tile & 15) * TM;
  const int n0 = (tile >> 4) * TN;
  const int K  = d.K;
  const int tid = threadIdx.x;

  __shared__ __align__(16) unsigned short Ah[TM*LDBS], Al[TM*LDBS];
  __shared__ __align__(16) unsigned short Bh[2][TN*32], Bl[2][TN*32];

  const int sr = tid >> 1;
  const int sk = (tid & 1) << 4;
  const int gmA = m0 + sr;
  const int wv = tid >> 6, lane = tid & 63;

  float4 pa[4];
  auto load_A = [&](int kt){
    const int kb = kt*32 + sk;
    #pragma unroll
    for (int u=0;u<4;++u)
      pa[u] = ld4(d.A + (size_t)gmA*K + kb + 4*u);
  };
  auto stage_B = [&](int kt, int buf){
    #pragma unroll
    for (int c=0;c<2;++c){
      const int rl  = (c<<4) + (lane>>2);          // row within wave slab, 0..31
      const int row = (wv<<5) + rl;
      const unsigned lk = (unsigned)(((lane&3) ^ ((rl>>1)&3)) << 4);  // logical kbyte
      const size_t gb = (((size_t)(n0 + row)*K + kt*32) << 1) + lk;   // byte offset
      char* db = (char*)(&Bh[buf][0]) + (wv<<11) + (c<<10);           // wave-uniform
      gl2lds16((const float*)((const char*)WH + gb), (float*)db);
      char* dl = (char*)(&Bl[buf][0]) + (wv<<11) + (c<<10);
      gl2lds16((const float*)((const char*)WL + gb), (float*)dl);
    }
  };

  const int wm = (wv >> 1) << 6, wn = (wv & 1) << 6;
  const int fr = lane & 15;
  const int fk = (lane >> 4) << 3;

  f32x4 acc[4][4];
  const f32x4 z4 = {0.f,0.f,0.f,0.f};
  #pragma unroll
  for (int i=0;i<4;++i)
    #pragma unroll
    for (int j=0;j<4;++j) acc[i][j]=z4;

  const int nslab = K >> 5;
  load_A(0);
  stage_B(0, 0);
  for (int kt=0; kt<nslab; ++kt){
    __syncthreads();                       // prior MFMA reads of Ah/Al done
    {
      unsigned hw[8], lw[8];
      #pragma unroll
      for (int u=0;u<4;++u){
        const float xs[4] = {pa[u].x, pa[u].y, pa[u].z, pa[u].w};
        split2(xs[0], xs[1], hw[u*2+0], lw[u*2+0]);
        split2(xs[2], xs[3], hw[u*2+1], lw[u*2+1]);
      }
      uint4 t;
      t.x=hw[0];t.y=hw[1];t.z=hw[2];t.w=hw[3]; *(uint4*)&Ah[sr*LDBS+sk]   = t;
      t.x=hw[4];t.y=hw[5];t.z=hw[6];t.w=hw[7]; *(uint4*)&Ah[sr*LDBS+sk+8] = t;
      t.x=lw[0];t.y=lw[1];t.z=lw[2];t.w=lw[3]; *(uint4*)&Al[sr*LDBS+sk]   = t;
      t.x=lw[4];t.y=lw[5];t.z=lw[6];t.w=lw[7]; *(uint4*)&Al[sr*LDBS+sk+8] = t;
    }
    __builtin_amdgcn_s_waitcnt(0x0F70);    // vmcnt(0): this tile's B-DMA landed
    __syncthreads();
    if (kt+1 < nslab){ load_A(kt+1); stage_B(kt+1, (kt+1)&1); }

    const unsigned short* BhT = &Bh[kt&1][0];
    const unsigned short* BlT = &Bl[kt&1][0];
    short8 bh4[4], bl4[4];
    #pragma unroll
    for (int nt=0;nt<4;++nt){
      const int rowB = wn + nt*16 + fr;
      const int so = rowB*32 + (fk ^ (((rowB>>1)&3)<<3));   // swizzled read
      bh4[nt] = *(const short8*)&BhT[so];
      bl4[nt] = *(const short8*)&BlT[so];
    }
    #pragma unroll
    for (int mt=0;mt<4;++mt){
      const short8 ah = *(const short8*)&Ah[(wm + mt*16 + fr)*LDBS + fk];
      const short8 al = *(const short8*)&Al[(wm + mt*16 + fr)*LDBS + fk];
      #pragma unroll
      for (int nt=0;nt<4;++nt)
        acc[mt][nt] = __builtin_amdgcn_mfma_f32_16x16x32_bf16(ah, bh4[nt], acc[mt][nt], 0,0,0);
      #pragma unroll
      for (int nt=0;nt<4;++nt)
        acc[mt][nt] = __builtin_amdgcn_mfma_f32_16x16x32_bf16(ah, bl4[nt], acc[mt][nt], 0,0,0);
      #pragma unroll
      for (int nt=0;nt<4;++nt)
        acc[mt][nt] = __builtin_amdgcn_mfma_f32_16x16x32_bf16(al, bh4[nt], acc[mt][nt], 0,0,0);
    }
  }

  #pragma unroll
  for (int mt=0;mt<4;++mt){
    #pragma unroll
    for (int nt=0;nt<4;++nt){
      #pragma unroll
      for (int r=0;r<4;++r){
        const int row = wm + mt*16 + ((lane>>4)<<2) + r;
        const int col = wn + nt*16 + fr;
        d.out[(size_t)(m0+row)*d.N + n0 + col] = acc[mt][nt][r];
      }
    }
  }
}

// ---------------- per-head prep (in-place coefficient precompute) ----------------
__global__ __launch_bounds__(256) void head_prep(
    float* kbuf, float* awbuf, float* svwbuf, float* wbbuf, float* vbuf,
    const float* __restrict__ vfirst,
    const float* __restrict__ k_k, const float* __restrict__ k_a)
{
  const int gid = blockIdx.x*4 + (threadIdx.x>>6);
  const int e = threadIdx.x & 63;
  const int m = gid >> 4;
  const int h = gid & 15;
  const int c = h*Dd + e;
  const size_t idx = (size_t)m*Cc + c;
  const float kv0 = kbuf[idx];
  const float av  = awbuf[idx];
  const float sv  = svwbuf[idx];
  const float wv  = wbbuf[idx];
  const float v0  = vbuf[idx];
  const float vf  = vfirst[idx];
  const float kku = kv0 * k_k[c];
  const float ss  = wredsum(kku*kku);
  const float kkn = kku / fmaxf(sqrtf(ss), 1e-12f);
  const float ew  = expf(wv);
  kbuf[idx]  = kv0 * (1.f + (av - 1.f)*k_a[c]);
  awbuf[idx] = ew;
  svwbuf[idx]= -kkn * ew;
  wbbuf[idx] = kkn * av;
  vbuf[idx]  = v0 + sv*(vf - v0);
}

// ---------------- scan v16: split-chain linear superposition -------------------
// The recurrence S_t = D_t S_{t-1} + k_t v_t^T (D_t = diag(ew)+bb law^T) is
// AFFINE in S, so each 1024-step chain splits into two 512-step halves:
//   blocks 0..511    (A):     t in [0,512), exact; writes S_mid at end.
//   blocks 512..1023 (B-real): t in [512,1024) with S(512)=0 (partial out).
//   blocks 1024..1535 (B-basis): 64 one-hot basis columns per chain evolve
//     under the same D_t (v masked to 0); their r-dots are bout[t][d'].
// fix_kernel then adds out[t,e] += sum_d bout[t][d] * S_mid[d][e] (exact
// linear superposition, fp32). Wall: 512 steps (~half), 1536 one-wave blocks,
// batch 8 (LDS 20.7 KB -> 7 blocks/CU, all co-resident; 2 waves/SIMD ~free
// per v12). Step body = v13 (bit-identical per-column math).
#define SB 8
#define SNB (HALF/SB)
#define LBF (5*SB*64 + 32)
struct Coef { float4 Lw, Ew, Bq, Kq, Rq; float Vv; };
__global__ __launch_bounds__(64) void scan_kernel(
    const float* __restrict__ lawb, const float* __restrict__ ewb,
    const float* __restrict__ bbb,  const float* __restrict__ kb,
    const float* __restrict__ rb,   const float* __restrict__ vb,
    float* __restrict__ outp, float* __restrict__ smid, float* __restrict__ bout)
{
  const int blk = blockIdx.x;       // 0..1535
  const bool isA = blk < 512;
  int bh, quad; bool basis = false;
  if (isA){ bh = blk & 31; quad = blk >> 5; }
  else {
    const int i = blk - 512;
    bh = i & 31;
    int q = i >> 5;                 // 0..31
    basis = (q >= 16);
    quad = basis ? (q - 16) : q;
  }
  const int tbase = isA ? 0 : HALF;
  const int b = bh >> 4, h = bh & 15;
  const int lane = threadIdx.x;
  const int es = lane >> 4;         // column slot 0..3
  const int rd = lane & 15;         // row quad (rows 4rd..4rd+3)
  const int colb = quad * 4;
  const int hb = h * Dd;
  const int la = 4*rd;

  __shared__ __align__(16) float LB[2][LBF];

  const float vmask = basis ? 0.f : 1.f;
  const int dsel = 4*quad + es;     // basis index owned by this lane's column slot
  float S0 = (basis && (4*rd+0 == dsel)) ? 1.f : 0.f;
  float S1 = (basis && (4*rd+1 == dsel)) ? 1.f : 0.f;
  float S2 = (basis && (4*rd+2 == dsel)) ? 1.f : 0.f;
  float S3 = (basis && (4*rd+3 == dsel)) ? 1.f : 0.f;
  float4 Rp = make_float4(0.f,0.f,0.f,0.f);
  const size_t mbase = (size_t)b*Tt + tbase;
  // output column base: real -> Batt column; basis -> bout column
  float* ocol  = outp + mbase*Cc + hb + colb + es;
  float* bcol  = bout + (size_t)bh*HALF*64 + dsel;

  const int qrow = lane >> 4;           // staging: row within 4-row slab
  const int qcol = (lane & 15) * 4;     // staging: dword col

  auto stage = [&](int bt){
    const size_t g0 = (mbase + (size_t)bt*SB)*Cc + hb;
    float* dst = &LB[bt&1][0];
    const float* srcs[5] = {lawb, ewb, bbb, kb, rb};
    #pragma unroll
    for (int a=0;a<5;++a){
      const float* s = srcs[a] + g0 + (size_t)qrow*Cc + qcol;
      #pragma unroll
      for (int i=0;i<2;++i)
        gl2lds16(s + (size_t)(4*i)*Cc, dst + a*(SB*64) + i*256);
    }
    if (lane < 32)
      gl2lds4(vb + g0 + (size_t)(lane>>2)*Cc + colb + (lane&3), dst + 5*SB*64);
  };

  stage(0);
  __builtin_amdgcn_s_waitcnt(0x0F70);   // vmcnt(0): batch 0's DMA complete

  for (int bt = 0; bt < SNB; ++bt){
    if (bt+1 < SNB) stage(bt+1);          // in flight under this batch's compute
    const float* cb2 = &LB[bt&1][0];

    auto ldq = [&](int t, Coef& c){
      c.Lw = *(const float4*)&cb2[0*SB*64 + t*64 + la];
      c.Ew = *(const float4*)&cb2[1*SB*64 + t*64 + la];
      c.Bq = *(const float4*)&cb2[2*SB*64 + t*64 + la];
      c.Kq = *(const float4*)&cb2[3*SB*64 + t*64 + la];
      c.Rq = *(const float4*)&cb2[4*SB*64 + t*64 + la];
      c.Vv = cb2[5*SB*64 + t*4 + es];
    };

    Coef cA, cB, cC, cD;
    ldq(0, cA); ldq(1, cB); ldq(2, cC); ldq(3, cD);

    auto stepf = [&](int t, Coef& c){
      const float4 Lw = c.Lw, Ew = c.Ew, Bq = c.Bq, Kq = c.Kq, rr = c.Rq;
      const float vv = c.Vv * vmask;
      float tp = fmaf(Lw.y, S1, Lw.x*S0);
      float tb = fmaf(Lw.w, S3, Lw.z*S2);
      tp += tb;
      float op = fmaf(Rp.y, S1, Rp.x*S0);
      float ob = fmaf(Rp.w, S3, Rp.z*S2);
      op += ob;
      dsum16x2(tp, op);
      const bool gv = (bt > 0) | (t > 0);
      if (gv && rd == 0){
        const int ti = bt*SB + t - 1;     // step index within half
        if (basis) bcol[(size_t)ti*64] = op;
        else       ocol[(size_t)ti*Cc] = op;
      }
      S0 = fmaf(Ew.x, S0, fmaf(Bq.x, tp, Kq.x*vv));
      S1 = fmaf(Ew.y, S1, fmaf(Bq.y, tp, Kq.y*vv));
      S2 = fmaf(Ew.z, S2, fmaf(Bq.z, tp, Kq.z*vv));
      S3 = fmaf(Ew.w, S3, fmaf(Bq.w, tp, Kq.w*vv));
      Rp = rr;
      if (t+4 < SB) ldq(t+4, c);
    };

    #pragma unroll
    for (int t = 0; t < SB; ++t){
      const int s = t & 3;
      if      (s == 0) stepf(t, cA);
      else if (s == 1) stepf(t, cB);
      else if (s == 2) stepf(t, cC);
      else             stepf(t, cD);
    }

    // counted wait: stage(bt+1)'s 11 DMA ops are oldest; <=SB stores after them.
    if (bt+1 < SNB) __builtin_amdgcn_s_waitcnt(0x0F78);   // vmcnt(8)
  }

  // flush: last step's out
  {
    float op = fmaf(Rp.y, S1, Rp.x*S0);
    float ob = fmaf(Rp.w, S3, Rp.z*S2);
    op = dsum16(op + ob);
    if (rd == 0){
      if (basis) bcol[(size_t)(HALF-1)*64] = op;
      else       ocol[(size_t)(HALF-1)*Cc] = op;
    }
  }

  // A blocks publish S_mid[bh][d][e]
  if (isA){
    #pragma unroll
    for (int j=0;j<4;++j){
      float s = (j==0)?S0:(j==1)?S1:(j==2)?S2:S3;
      smid[(size_t)bh*4096 + (size_t)(4*rd+j)*64 + colb + es] = s;
    }
  }
}

// ---------------- fix: out[512+t][e] += sum_d bout[t][d] * S_mid[d][e] ------------
__global__ __launch_bounds__(256) void fix_kernel(
    float* __restrict__ outp, const float* __restrict__ smid,
    const float* __restrict__ bout)
{
  __shared__ float SM[64*64];
  __shared__ float BR[4][64];
  const int chain = blockIdx.x >> 3;     // 0..31
  const int slab  = blockIdx.x & 7;      // 0..7 (64 t each)
  const int tid = threadIdx.x;
  const int wv = tid >> 6, e = tid & 63;
  const int b = chain >> 4, h = chain & 15;
  #pragma unroll
  for (int i=0;i<16;++i) SM[tid + i*256] = smid[(size_t)chain*4096 + tid + i*256];
  __syncthreads();
  float* ocol = outp + ((size_t)(b*Tt + HALF + slab*64))*Cc + h*Dd + e;
  const float* brow = bout + ((size_t)chain*HALF + slab*64)*64;
  for (int tt=0; tt<16; ++tt){
    const int t = wv*16 + tt;            // 0..63 within slab
    BR[wv][e] = brow[(size_t)t*64 + e];  // wave stages its bout row (wave-local)
    float acc = ocol[(size_t)t*Cc];
    #pragma unroll 16
    for (int d=0; d<64; ++d)
      acc = fmaf(BR[wv][d], SM[d*64 + e], acc);
    ocol[(size_t)t*Cc] = acc;
  }
}

// ---------------- GroupNorm + correction + g gating ----------------
__global__ __launch_bounds__(256) void epilogue_kernel(
    const float* __restrict__ att, const float* __restrict__ rbuf,
    const float* __restrict__ kbuf, const float* __restrict__ vbuf,
    const float* __restrict__ gbuf,
    const float* __restrict__ r_k, const float* __restrict__ gn_w,
    const float* __restrict__ gn_b, float* __restrict__ opre)
{
  const int gid = blockIdx.x*4 + (threadIdx.x>>6);
  const int e = threadIdx.x & 63;
  const int m = gid >> 4;
  const int h = gid & 15;
  const int c = h*Dd + e;
  const size_t idx = (size_t)m*Cc + c;
  const float x  = att[idx];
  const float mu = wredsum(x) * (1.f/Dd);
  const float xd = x - mu;
  const float var = wredsum(xd*xd) * (1.f/Dd);
  const float og = xd * (1.f/sqrtf(var + GN_EPS)) * gn_w[c] + gn_b[c];
  const float rv = rbuf[idx], kv = kbuf[idx], vv = vbuf[idx];
  const float cd = wredsum(rv*kv*r_k[c]);
  opre[idx] = (og + cd*vv) * gbuf[idx];
}

extern "C" void kernel_launch(void* const* d_in, const int* in_sizes, int n_in,
                              void* d_out, int out_size, void* d_ws, size_t ws_size,
                              hipStream_t stream)
{
  (void)in_sizes; (void)n_in; (void)out_size; (void)ws_size;
  const float* hs     = (const float*)d_in[0];
  const float* vfirst = (const float*)d_in[1];
  const float* xmix   = (const float*)d_in[2];
  const float* k_k    = (const float*)d_in[3];
  const float* k_a    = (const float*)d_in[4];
  const float* r_k    = (const float*)d_in[5];
  const float* W_r    = (const float*)d_in[6];
  const float* W_k    = (const float*)d_in[7];
  const float* W_v    = (const float*)d_in[8];
  const float* W_o    = (const float*)d_in[9];
  const float* w_A    = (const float*)d_in[10];
  const float* w_B    = (const float*)d_in[11];
  const float* w_b    = (const float*)d_in[12];
  const float* a_A    = (const float*)d_in[13];
  const float* a_B    = (const float*)d_in[14];
  const float* a_b    = (const float*)d_in[15];
  const float* v_A    = (const float*)d_in[16];
  const float* v_B    = (const float*)d_in[17];
  const float* v_b    = (const float*)d_in[18];
  const float* g_A    = (const float*)d_in[19];
  const float* g_B    = (const float*)d_in[20];
  const float* gn_w   = (const float*)d_in[21];
  const float* gn_b   = (const float*)d_in[22];
  float* out = (float*)d_out;
  float* ws  = (float*)d_ws;

  const size_t MC = (size_t)Mm * Cc;
  float* Br   = ws;            // r
  float* Bw   = ws + MC;       // [premix xr] -> w/bb (L3/L4) -> o_pre (epilogue)
  float* Bk   = ws + 2*MC;     // k0 -> kfin
  float* Bkk  = ws + 3*MC;     // [premix xk] -> sv -> law
  float* Bv   = ws + 4*MC;     // v0 -> v
  float* Ba   = ws + 5*MC;     // [premix xv] -> a -> ew
  float* Batt = ws + 6*MC;     // scan output
  float* Bg   = ws + 7*MC;     // g
  float* T1w  = ws + 8*MC;
  float* T1a  = T1w + (size_t)Mm*64;
  float* T1v  = T1a + (size_t)Mm*64;
  float* T1g  = T1v + (size_t)Mm*64;   // Mm*160 floats
  unsigned short* WP = (unsigned short*)(ws + 8*MC + (size_t)Mm*352);
  unsigned short* WrH = WP + 0*(size_t)NPL, *WrL = WP + 1*(size_t)NPL;
  unsigned short* WkH = WP + 2*(size_t)NPL, *WkL = WP + 3*(size_t)NPL;
  unsigned short* WvH = WP + 4*(size_t)NPL, *WvL = WP + 5*(size_t)NPL;
  unsigned short* WoH = WP + 6*(size_t)NPL, *WoL = WP + 7*(size_t)NPL;
  // scan split-chain scratch: lives in the Wr/Wk plane region (dead after L1)
  float* BOUT = (float*)WP;                    // 32*512*64 floats = 4 MB
  float* SMID = (float*)WP + (size_t)32*HALF*64;   // 32*64*64 floats = 512 KB

  dim3 blk(256,1,1);

  // L0: fused weight split + fp32 premix (xr -> Bw, xk -> Bkk, xv -> Ba)
  prep_kernel<<<dim3(Mm*Cc/(256*4),1,7), blk, 0, stream>>>(
      W_r, W_k, W_v, W_o, WP, hs, xmix, Bw, Bkk, Ba);

  // L1: big projections r, k0, v0 via split-bf16 MFMA
  GemmDesc dr{Bw,  W_r, Br, nullptr, Cc, Cc, -1, 0};
  GemmDesc dk{Bkk, W_k, Bk, nullptr, Cc, Cc, -1, 0};
  GemmDesc dv{Ba,  W_v, Bv, nullptr, Cc, Cc, -1, 0};
  gemm_mfma<<<dim3(Cc/TN, Mm/TM, 3), blk, 0, stream>>>(
      dr, dk, dv, WrH, WrL, WkH, WkL, WvH, WvL);

  // L2: LoRA stage-1 (w/a/v on 64-wide path, g on 128-wide path)
  GemmDesc s1w{nullptr, w_A, T1w, nullptr, 64, Cc, 1, 1};
  GemmDesc s1a{nullptr, a_A, T1a, nullptr, 64, Cc, 4, 0};
  GemmDesc s1v{nullptr, v_A, T1v, nullptr, 64, Cc, 3, 0};
  GemmDesc s1g{nullptr, g_A, T1g, nullptr, 160, Cc, 5, 2};
  lora1_kernel<<<dim3(2,32,4), blk, 0, stream>>>(s1w,s1a,s1v,s1g, xmix, hs);

  // L3: LoRA stage-2
  GemmDesc s2w{T1w, w_B, Bw,  w_b,    Cc, 64,  -1, 3};
  GemmDesc s2a{T1a, a_B, Ba,  a_b,    Cc, 64,  -1, 2};
  GemmDesc s2v{T1v, v_B, Bkk, v_b,    Cc, 64,  -1, 2};
  GemmDesc s2g{T1g, g_B, Bg,  nullptr,Cc, 160, -1, 0};
  gemm_kernel<<<dim3(8,32,4), blk, 0, stream>>>(s2w,s2a,s2v,s2g, xmix, hs);

  // L4: per-head prep
  head_prep<<<dim3(Mm*Hh/4), blk, 0, stream>>>(Bk, Ba, Bkk, Bw, Bv,
                                               vfirst, k_k, k_a);

  // L5: split-chain scan (v16): 1536 one-wave blocks, 512 steps each
  scan_kernel<<<dim3(1536), dim3(64), 0, stream>>>(Bkk, Ba, Bw, Bk, Br, Bv,
                                                   Batt, SMID, BOUT);

  // L5b: linear-superposition correction for t >= 512
  fix_kernel<<<dim3(256), blk, 0, stream>>>(Batt, SMID, BOUT);

  // L6: groupnorm + corr + g -> o_pre
  epilogue_kernel<<<dim3(Mm*Hh/4), blk, 0, stream>>>(Batt, Br, Bk, Bv, Bg,
                                                     r_k, gn_w, gn_b, Bw);

  // L7: output projection via split-bf16 MFMA
  GemmDesc doo{Bw, W_o, out, nullptr, Cc, Cc, -1, 0};
  gemm_mfma<<<dim3(Cc/TN, Mm/TM, 1), blk, 0, stream>>>(
      doo, doo, doo, WoH, WoL, WoH, WoL, WoH, WoL);
}